// Round 1
// baseline (506.837 us; speedup 1.0000x reference)
//
#include <hip/hip_runtime.h>
#include <hip/hip_bf16.h>

#define N_NODES 10000
#define E_TOT   320000

typedef __attribute__((ext_vector_type(8))) short short8;
typedef __attribute__((ext_vector_type(4))) float f32x4;

// ---- workspace byte offsets (16B-aligned; total ~49.4 MB) ----
#define HIST_OFF    0u            // N int (zeroed)
#define FILL_OFF    40000u        // N int (zeroed)
#define ZERO_BYTES  80000u        // memset [0, here) -- only the sort counters!
#define ROWPTR_OFF  80000u        // (N+1) int (fully written by scan)
#define PERM_OFF    120064u       // E int
#define PSRC_OFF    1400064u      // E int
#define PQ_OFF      2680064u      // N*416 bf16 [P(204)+pad | Q(204)+pad]
#define QV_OFF      11000064u     // N*96 bf16
#define WHV4_OFF    12920064u     // 128 f32
#define WBIG_OFF    12920576u     // 256*672 bf16 = 344,064  mega scalar GEMM W^T
#define NSBF_OFF    13264640u     // N*256 bf16
#define ANSB_OFF    18384640u     // N*256 bf16  (sum ns[src])/deg
#define EAB_OFF     23504640u     // N*160 bf16  [AES(64)|AVN(68)|pad(28)]/deg
#define AP_OFF      26704640u     // N*204 f32   sum P[src]
#define AEV_OFF     34864640u     // N*12 f32    sum edge_v
#define NODES_OFF   35344640u     // N*256 f32   scalar output pre-bias
#define AGGV_OFF    45584640u     // N*96 f32
#define FLAGS_OFF   49424640u     // 2 ints

union BfS { __hip_bfloat16 h; short s; };
__device__ __forceinline__ short f2bf(float x) { BfS u; u.h = __float2bfloat16(x); return u.s; }
__device__ __forceinline__ float bf(short x) { BfS u; u.s = x; return __bfloat162float(u.h); }
__device__ __forceinline__ float ldin(const void* p, int f32m, long i) {
  return f32m ? ((const float*)p)[i] : __bfloat162float(((const __hip_bfloat16*)p)[i]);
}
__device__ __forceinline__ int get_ei(const void* p, int i64m, long i) {
  return i64m ? (int)(((const long long*)p)[i]) : ((const int*)p)[i];
}

// ---------------------------------------------------------------------------
__global__ __launch_bounds__(256) void detect_kernel(
    const unsigned short* __restrict__ ns_u16,
    const int* __restrict__ ei_i32, int* __restrict__ flags)
{
  __shared__ int cf, ci;
  if (threadIdx.x == 0) { cf = 0; ci = 0; }
  __syncthreads();
  int c1 = 0;
  for (int i = threadIdx.x; i < 8192; i += 256) {
    unsigned e = (ns_u16[2 * i] >> 7) & 0xFF;
    if (e < 100 || e > 140) c1++;
  }
  int c2 = 0;
  for (int i = threadIdx.x; i < 4096; i += 256)
    if (ei_i32[2 * i + 1] != 0) c2++;
  atomicAdd(&cf, c1); atomicAdd(&ci, c2);
  __syncthreads();
  if (threadIdx.x == 0) {
    flags[0] = (cf > 512) ? 1 : 0;   // 1 => f32 inputs
    flags[1] = (ci < 100) ? 1 : 0;   // 1 => int64 edge_index
  }
}

// ---------------------------------------------------------------------------
__global__ __launch_bounds__(256) void hist_kernel(
    const void* __restrict__ edge_index, const int* __restrict__ flags,
    int* __restrict__ hist)
{
  const int i64m = flags[1];
  int e = blockIdx.x * 256 + threadIdx.x;
  int dst = get_ei(edge_index, i64m, (long)E_TOT + e);
  atomicAdd(&hist[dst], 1);
}

__global__ __launch_bounds__(256) void scan_kernel(
    const int* __restrict__ hist, int* __restrict__ rowptr)
{
  __shared__ int part[256];
  int tid = threadIdx.x;
  int base = tid * 40;
  int s = 0;
  for (int i = 0; i < 40; ++i) { int idx = base + i; if (idx < N_NODES) s += hist[idx]; }
  part[tid] = s;
  __syncthreads();
  for (int off = 1; off < 256; off <<= 1) {
    int v = (tid >= off) ? part[tid - off] : 0;
    __syncthreads();
    part[tid] += v;
    __syncthreads();
  }
  int run = (tid > 0) ? part[tid - 1] : 0;
  for (int i = 0; i < 40; ++i) {
    int idx = base + i;
    if (idx < N_NODES) { rowptr[idx] = run; run += hist[idx]; }
  }
  if (tid == 255) rowptr[N_NODES] = run;
}

__global__ __launch_bounds__(256) void permute_kernel(
    const void* __restrict__ edge_index, const int* __restrict__ flags,
    const int* __restrict__ rowptr, int* __restrict__ fill,
    int* __restrict__ perm, int* __restrict__ psrc)
{
  const int i64m = flags[1];
  int e = blockIdx.x * 256 + threadIdx.x;
  int dst = get_ei(edge_index, i64m, (long)E_TOT + e);
  int src = get_ei(edge_index, i64m, e);
  int pos = rowptr[dst] + atomicAdd(&fill[dst], 1);
  perm[pos] = e; psrc[pos] = src;
}

// ---------------------------------------------------------------------------
// prep: Wbig^T[o][k<672]: k<320 -> ws_w row k (src ns + edge_s);
//       320..387 -> rows 576..643 (vn); 388..415 -> 0; 416..671 -> rows
//       320..575 (dst ns, i.e. r = k-96). Block 672: whv4 = wh[32:36]@wv.
// ---------------------------------------------------------------------------
__global__ __launch_bounds__(256) void prep_kernel(
    const void* __restrict__ ws_w, const void* __restrict__ wh,
    const void* __restrict__ wv, const int* __restrict__ flags,
    short* __restrict__ Wbig, float* __restrict__ whv4)
{
  const int f32m = flags[0];
  int b = blockIdx.x, tid = threadIdx.x;
  if (b < 672) {
    int flat = b * 256 + tid;           // = o*672 + k
    int o = flat / 672, k = flat % 672;
    short v = 0;
    if (k < 320)      v = f2bf(ldin(ws_w, f32m, (long)k * 256 + o));
    else if (k < 388) v = f2bf(ldin(ws_w, f32m, (long)(576 + k - 320) * 256 + o));
    else if (k >= 416) v = f2bf(ldin(ws_w, f32m, (long)(k - 96) * 256 + o));
    Wbig[flat] = v;
  } else if (tid < 128) {
    int q = tid / 32, c = tid % 32;
    float acc = 0.f;
    for (int h = 0; h < 68; ++h)
      acc += ldin(wh, f32m, (32 + q) * 68 + h) * ldin(wv, f32m, h * 32 + c);
    whv4[tid] = acc;
  }
}

__global__ __launch_bounds__(256) void nsconv_kernel(
    const void* __restrict__ node_s, const int* __restrict__ flags,
    short* __restrict__ ns_bf)
{
  const int f32m = flags[0];
  int i = blockIdx.x * 256 + threadIdx.x;
  ns_bf[i] = f2bf(ldin(node_s, f32m, i));
}

// ---------------------------------------------------------------------------
// node_pre: per 4 nodes — PQ = [P|Q] bf16 (padded 208 each), Qv bf16.
// ---------------------------------------------------------------------------
__global__ __launch_bounds__(256) void node_pre(
    const void* __restrict__ node_v, const void* __restrict__ wh,
    const void* __restrict__ wv, const int* __restrict__ flags,
    short* __restrict__ PQ, short* __restrict__ QV)
{
  const int f32m = flags[0];
  int n0 = blockIdx.x * 4, tid = threadIdx.x;
  __shared__ float nv[4][96];
  __shared__ float pq[4][408];
  for (int i = tid; i < 4 * 96; i += 256) nv[i / 96][i % 96] = ldin(node_v, f32m, (long)n0 * 96 + i);
  __syncthreads();
  for (int o = tid; o < 4 * 408; o += 256) {
    int i = o / 408, r0 = o % 408;
    int part = r0 / 204, r = r0 % 204, d = r / 68, h = r % 68;
    int cbase = part ? 36 : 0;
    float acc = 0.f;
#pragma unroll
    for (int c = 0; c < 32; ++c)
      acc += nv[i][c * 3 + d] * ldin(wh, f32m, (cbase + c) * 68 + h);
    pq[i][r0] = acc;
  }
  __syncthreads();
  for (int o = tid; o < 4 * 416; o += 256) {
    int i = o / 416, k = o % 416, part = k / 208, r = k % 208;
    PQ[(long)(n0 + i) * 416 + k] = (r < 204) ? f2bf(pq[i][part * 204 + r]) : (short)0;
  }
  for (int o = tid; o < 4 * 96; o += 256) {
    int i = o / 96, r = o % 96, d = r / 32, c = r % 32;
    float acc = 0.f;
    for (int h = 0; h < 68; ++h)
      acc += pq[i][204 + d * 68 + h] * ldin(wv, f32m, h * 32 + c);
    QV[(long)(n0 + i) * 96 + r] = f2bf(acc);
  }
}

// ---------------------------------------------------------------------------
// edge_node: one block per dst. 8-edge chunks; vn computed IN LDS ONLY.
// Direct-writes (no atomics, no global vn): ANS/deg, [AES|AVN]/deg, AP, AEV.
// ---------------------------------------------------------------------------
__global__ __launch_bounds__(256) void edge_node(
    const void* __restrict__ edge_v, const void* __restrict__ edge_s,
    const void* __restrict__ wh, const int* __restrict__ flags,
    const int* __restrict__ rowptr, const int* __restrict__ perm,
    const int* __restrict__ psrc, const short* __restrict__ PQ,
    const short* __restrict__ nsb,
    short* __restrict__ ANSb, short* __restrict__ EAb,
    float* __restrict__ AP, float* __restrict__ AEV)
{
  const int f32m = flags[0];
  const int n = blockIdx.x, tid = threadIdx.x;
  const int beg = rowptr[n], deg = rowptr[n + 1] - beg;
  __shared__ float Qs[204];
  __shared__ float whs4[272];
  __shared__ __align__(16) short PsL[8 * 208];
  __shared__ float evL[8 * 12];
  __shared__ float esL[8 * 64];
  __shared__ float vnL[8 * 68];
  __shared__ int svL[8], eidL[8];
  for (int i = tid; i < 204; i += 256) Qs[i] = bf(PQ[(long)n * 416 + 208 + i]);
  for (int i = tid; i < 272; i += 256) whs4[i] = ldin(wh, f32m, (32 + i / 68) * 68 + i % 68);
  float ansc = 0.f, apc = 0.f, aev = 0.f, aesc = 0.f, avnc = 0.f;
  const int pe = tid >> 5, pc = tid & 31;
  for (int c0 = 0; c0 < deg; c0 += 8) {
    int m = min(8, deg - c0);
    __syncthreads();                 // B1: prev-iter LDS readers done
    if (tid < m) { svL[tid] = psrc[beg + c0 + tid]; eidL[tid] = perm[beg + c0 + tid]; }
    __syncthreads();                 // B2: indices ready
    if (pe < m && pc < 26)
      *(short8*)&PsL[pe * 208 + pc * 8] = *(const short8*)&PQ[(long)svL[pe] * 416 + pc * 8];
    for (int i = tid; i < m * 12; i += 256)
      evL[i] = ldin(edge_v, f32m, (long)eidL[i / 12] * 12 + i % 12);
    for (int i = tid; i < m * 64; i += 256)
      esL[i] = ldin(edge_s, f32m, (long)eidL[i >> 6] * 64 + (i & 63));
    for (int e = 0; e < m; ++e)      // ANS gather (coalesced 512B rows, L2)
      ansc += bf(nsb[(long)svL[e] * 256 + tid]);
    __syncthreads();                 // B3: staging ready
    // vn -> vnL
#pragma unroll
    for (int j = 0; j < 3; ++j) {
      int h = pc + 32 * j;
      if (pe < m && h < 68) {
        float ss = 0.f;
#pragma unroll
        for (int d = 0; d < 3; ++d) {
          float v = bf(PsL[pe * 208 + d * 68 + h]) + Qs[d * 68 + h]
                  + evL[pe * 12 + d]     * whs4[h]       + evL[pe * 12 + 3 + d] * whs4[68 + h]
                  + evL[pe * 12 + 6 + d] * whs4[136 + h] + evL[pe * 12 + 9 + d] * whs4[204 + h];
          ss += v * v;
        }
        vnL[pe * 68 + h] = sqrtf(fmaxf(ss, 1e-8f));
      }
    }
    if (tid < 204) { for (int e = 0; e < m; ++e) apc += bf(PsL[e * 208 + tid]); }
    else if (tid < 216) { int c = tid - 204; for (int e = 0; e < m; ++e) aev += evL[e * 12 + c]; }
    if (tid < 64)  { for (int e = 0; e < m; ++e) aesc += esL[e * 64 + tid]; }
    __syncthreads();                 // B4: vnL ready
    if (tid < 68)  { for (int e = 0; e < m; ++e) avnc += vnL[e * 68 + tid]; }
  }
  float inv = 1.f / fmaxf((float)deg, 1.f);
  ANSb[(long)n * 256 + tid] = f2bf(ansc * inv);
  if (tid < 204) AP[(long)n * 204 + tid] = apc;
  else if (tid < 216) AEV[(long)n * 12 + tid - 204] = aev;
  if (tid < 64) EAb[(long)n * 160 + tid] = f2bf(aesc * inv);
  if (tid < 68) EAb[(long)n * 160 + 64 + tid] = f2bf(avnc * inv);
  if (tid >= 132 && tid < 160) EAb[(long)n * 160 + tid] = 0;
}

// ---------------------------------------------------------------------------
// node_gemm: NodeS[n] = [ANS/deg | AES/deg|AVN/deg | ns] @ Wbig
// ([N,672]@[672,256]); 64 rows/block, 21 K-slabs, direct f32 stores.
// ---------------------------------------------------------------------------
__global__ __launch_bounds__(256) void node_gemm(
    const short* __restrict__ ANSb, const short* __restrict__ EAb,
    const short* __restrict__ nsb, const short* __restrict__ Wbig,
    float* __restrict__ NodeS)
{
  __shared__ __align__(16) short Xs[64 * 40];
  __shared__ __align__(16) short Ws[256 * 40];
  const int tid = threadIdx.x;
  const int n0 = blockIdx.x * 64;
  const int lane = tid & 63, wave = tid >> 6;
  const int frow = lane & 15, fk = (lane >> 4) * 8, q = lane >> 4;
  f32x4 acc[4][4];
#pragma unroll
  for (int ri = 0; ri < 4; ++ri)
#pragma unroll
    for (int ci = 0; ci < 4; ++ci)
      acc[ri][ci] = (f32x4){0.f, 0.f, 0.f, 0.f};
  const int se = tid >> 2, sq = tid & 3;
  const int rn = min(n0 + se, N_NODES - 1);
  for (int s = 0; s < 21; ++s) {
    short8 xv;
    if (s < 8)       xv = *(const short8*)&ANSb[(long)rn * 256 + s * 32 + sq * 8];
    else if (s < 13) xv = *(const short8*)&EAb[(long)rn * 160 + (s - 8) * 32 + sq * 8];
    else             xv = *(const short8*)&nsb[(long)rn * 256 + (s - 13) * 32 + sq * 8];
    *(short8*)&Xs[se * 40 + sq * 8] = xv;
#pragma unroll
    for (int it = 0; it < 4; ++it) {
      int flat = it * 256 + tid;
      int nn = flat >> 2, qq = flat & 3;
      *(short8*)&Ws[nn * 40 + qq * 8] = *(const short8*)&Wbig[nn * 672 + s * 32 + qq * 8];
    }
    __syncthreads();
    short8 a[4];
#pragma unroll
    for (int ri = 0; ri < 4; ++ri)
      a[ri] = *(const short8*)&Xs[(ri * 16 + frow) * 40 + fk];
#pragma unroll
    for (int ci = 0; ci < 4; ++ci) {
      int nn = wave * 64 + ci * 16 + frow;
      short8 b = *(const short8*)&Ws[nn * 40 + fk];
#pragma unroll
      for (int ri = 0; ri < 4; ++ri)
        acc[ri][ci] = __builtin_amdgcn_mfma_f32_16x16x32_bf16(a[ri], b, acc[ri][ci], 0, 0, 0);
    }
    __syncthreads();
  }
#pragma unroll
  for (int ri = 0; ri < 4; ++ri)
#pragma unroll
    for (int rr = 0; rr < 4; ++rr) {
      int row = n0 + ri * 16 + q * 4 + rr;
      if (row < N_NODES) {
#pragma unroll
        for (int ci = 0; ci < 4; ++ci) {
          int col = wave * 64 + ci * 16 + (lane & 15);
          NodeS[(long)row * 256 + col] = acc[ri][ci][rr];
        }
      }
    }
}

// ---------------------------------------------------------------------------
// nodev: agg_v[n] = AP[n] @ wv + AEV[n] @ whv4   (4 nodes/block)
// ---------------------------------------------------------------------------
__global__ __launch_bounds__(256) void nodev_kernel(
    const float* __restrict__ AP, const float* __restrict__ AEV,
    const void* __restrict__ wv, const float* __restrict__ whv4,
    const int* __restrict__ flags, float* __restrict__ agg_v)
{
  const int f32m = flags[0];
  int n0 = blockIdx.x * 4, tid = threadIdx.x;
  __shared__ float wvs[68 * 32];
  __shared__ float wh4s[128];
  __shared__ float APs[4][204];
  __shared__ float AEVs[4][12];
  for (int i = tid; i < 2176; i += 256) wvs[i] = ldin(wv, f32m, i);
  if (tid < 128) wh4s[tid] = whv4[tid];
  for (int i = tid; i < 816; i += 256) APs[i / 204][i % 204] = AP[(long)n0 * 204 + i];
  if (tid < 48) AEVs[tid / 12][tid % 12] = AEV[(long)n0 * 12 + tid];
  __syncthreads();
  for (int o = tid; o < 384; o += 256) {
    int i = o / 96, r = o % 96, c = r / 3, d = r % 3;
    float acc = AEVs[i][d] * wh4s[c] + AEVs[i][3 + d] * wh4s[32 + c]
              + AEVs[i][6 + d] * wh4s[64 + c] + AEVs[i][9 + d] * wh4s[96 + c];
    for (int h = 0; h < 68; ++h)
      acc += APs[i][d * 68 + h] * wvs[h * 32 + c];
    agg_v[(long)(n0 + i) * 96 + r] = acc;
  }
}

// ---------------------------------------------------------------------------
__global__ __launch_bounds__(256) void finalize(
    const float* __restrict__ NodeS, const float* __restrict__ agg_v,
    const int* __restrict__ rowptr, const short* __restrict__ QV,
    const void* __restrict__ ws_b, const int* __restrict__ flags,
    void* __restrict__ out)
{
  const int f32m = flags[0];
  int flat = blockIdx.x * 256 + threadIdx.x;   // N*352 exact
  int n = flat / 352, j = flat % 352;
  int deg = rowptr[n + 1] - rowptr[n];
  float v;
  if (j < 256) {
    v = (deg > 0) ? (NodeS[(long)n * 256 + j] + ldin(ws_b, f32m, j)) : 0.f;
  } else {
    int m = j - 256, ch = m / 3, d = m % 3;
    float inv = 1.f / fmaxf((float)deg, 1.f);
    v = agg_v[(long)n * 96 + m] * inv;
    if (deg > 0) v += bf(QV[(long)n * 96 + d * 32 + ch]);
  }
  if (f32m) ((float*)out)[flat] = v;
  else      ((__hip_bfloat16*)out)[flat] = __float2bfloat16(v);
}

extern "C" void kernel_launch(void* const* d_in, const int* in_sizes, int n_in,
                              void* d_out, int out_size, void* d_ws, size_t ws_size,
                              hipStream_t stream) {
  const void* node_s = d_in[0];
  const void* node_v = d_in[1];
  const void* edge_s = d_in[2];
  const void* edge_v = d_in[3];
  const void* wh     = d_in[4];
  const void* ws_w   = d_in[5];
  const void* ws_b   = d_in[6];
  const void* wv     = d_in[7];
  const void* edge_index = d_in[8];

  char* ws = (char*)d_ws;
  int*   hist  = (int*)(ws + HIST_OFF);
  int*   fill  = (int*)(ws + FILL_OFF);
  int*   rowptr= (int*)(ws + ROWPTR_OFF);
  int*   perm  = (int*)(ws + PERM_OFF);
  int*   psrc  = (int*)(ws + PSRC_OFF);
  short* PQ    = (short*)(ws + PQ_OFF);
  short* QV    = (short*)(ws + QV_OFF);
  float* whv4  = (float*)(ws + WHV4_OFF);
  short* Wbig  = (short*)(ws + WBIG_OFF);
  short* ns_bf = (short*)(ws + NSBF_OFF);
  short* ANSb  = (short*)(ws + ANSB_OFF);
  short* EAb   = (short*)(ws + EAB_OFF);
  float* AP    = (float*)(ws + AP_OFF);
  float* AEV   = (float*)(ws + AEV_OFF);
  float* NodeS = (float*)(ws + NODES_OFF);
  float* agg_v = (float*)(ws + AGGV_OFF);
  int*   flags = (int*)(ws + FLAGS_OFF);

  hipMemsetAsync(d_ws, 0, ZERO_BYTES, stream);
  detect_kernel<<<1, 256, 0, stream>>>((const unsigned short*)node_s,
                                       (const int*)edge_index, flags);
  hist_kernel<<<1250, 256, 0, stream>>>(edge_index, flags, hist);
  scan_kernel<<<1, 256, 0, stream>>>(hist, rowptr);
  permute_kernel<<<1250, 256, 0, stream>>>(edge_index, flags, rowptr, fill,
                                           perm, psrc);
  prep_kernel<<<673, 256, 0, stream>>>(ws_w, wh, wv, flags, Wbig, whv4);
  nsconv_kernel<<<10000, 256, 0, stream>>>(node_s, flags, ns_bf);
  node_pre<<<2500, 256, 0, stream>>>(node_v, wh, wv, flags, PQ, QV);
  edge_node<<<10000, 256, 0, stream>>>(edge_v, edge_s, wh, flags, rowptr,
                                       perm, psrc, PQ, ns_bf,
                                       ANSb, EAb, AP, AEV);
  node_gemm<<<157, 256, 0, stream>>>(ANSb, EAb, ns_bf, Wbig, NodeS);
  nodev_kernel<<<2500, 256, 0, stream>>>(AP, AEV, wv, whv4, flags, agg_v);
  finalize<<<13750, 256, 0, stream>>>(NodeS, agg_v, rowptr, QV, ws_b,
                                      flags, d_out);
}

// Round 3
// 488.265 us; speedup vs baseline: 1.0380x; 1.0380x over previous
//
#include <hip/hip_runtime.h>
#include <hip/hip_bf16.h>

#define N_NODES 10000
#define E_TOT   320000

typedef __attribute__((ext_vector_type(8))) short short8;
typedef __attribute__((ext_vector_type(4))) short s16x4;
typedef __attribute__((ext_vector_type(4))) float f32x4;

// ---- workspace byte offsets (16B-aligned; total ~40.5 MB) ----
#define HIST_OFF    0u            // N int (zeroed)
#define FILL_OFF    40000u        // N int (zeroed)
#define ZERO_BYTES  80000u        // memset [0, here) -- only the sort counters!
#define ROWPTR_OFF  80000u        // (N+1) int (fully written by scan)
#define PERM_OFF    120064u       // E int
#define PSRC_OFF    1400064u      // E int
#define PQ_OFF      2680064u      // N*480 shorts: P'(272, h*4+d pad) | Q(204, d*68+h) | pad4
#define QV_OFF      12280064u     // N*96 bf16
#define WHV4_OFF    14200064u     // 128 f32
#define WBIG_OFF    14200576u     // 256*672 bf16 = 344,064  mega scalar GEMM W^T
#define NSBF_OFF    14544640u     // N*256 bf16
#define ANSB_OFF    19664640u     // N*256 bf16  (sum ns[src])/deg
#define EAB_OFF     24784640u     // N*160 bf16  [AES(64)|AVN(68)|pad(28)]/deg
#define AP_OFF      27984640u     // N*204 f32   sum P[src], layout [h*3+d]
#define AEV_OFF     36144640u     // N*12 f32    sum edge_v
#define AGGV_OFF    36624640u     // N*96 f32
#define FLAGS_OFF   40464640u     // 2 ints
// NodeS (N*256 f32 = 10.24MB) aliases [PERM_OFF, ...) -- perm/psrc/PQ are
// dead by the time node_gemm writes it; rowptr (ends 120004) untouched.
#define NODES_OFF   120064u

union BfS { __hip_bfloat16 h; short s; };
__device__ __forceinline__ short f2bf(float x) { BfS u; u.h = __float2bfloat16(x); return u.s; }
__device__ __forceinline__ float bf(short x) { BfS u; u.s = x; return __bfloat162float(u.h); }
__device__ __forceinline__ float ldin(const void* p, int f32m, long i) {
  return f32m ? ((const float*)p)[i] : __bfloat162float(((const __hip_bfloat16*)p)[i]);
}
__device__ __forceinline__ int get_ei(const void* p, int i64m, long i) {
  return i64m ? (int)(((const long long*)p)[i]) : ((const int*)p)[i];
}

// ---------------------------------------------------------------------------
__global__ __launch_bounds__(256) void detect_kernel(
    const unsigned short* __restrict__ ns_u16,
    const int* __restrict__ ei_i32, int* __restrict__ flags)
{
  __shared__ int cf, ci;
  if (threadIdx.x == 0) { cf = 0; ci = 0; }
  __syncthreads();
  int c1 = 0;
  for (int i = threadIdx.x; i < 8192; i += 256) {
    unsigned e = (ns_u16[2 * i] >> 7) & 0xFF;
    if (e < 100 || e > 140) c1++;
  }
  int c2 = 0;
  for (int i = threadIdx.x; i < 4096; i += 256)
    if (ei_i32[2 * i + 1] != 0) c2++;
  atomicAdd(&cf, c1); atomicAdd(&ci, c2);
  __syncthreads();
  if (threadIdx.x == 0) {
    flags[0] = (cf > 512) ? 1 : 0;   // 1 => f32 inputs
    flags[1] = (ci < 100) ? 1 : 0;   // 1 => int64 edge_index
  }
}

// ---------------------------------------------------------------------------
__global__ __launch_bounds__(256) void hist_kernel(
    const void* __restrict__ edge_index, const int* __restrict__ flags,
    int* __restrict__ hist)
{
  const int i64m = flags[1];
  int e = blockIdx.x * 256 + threadIdx.x;
  int dst = get_ei(edge_index, i64m, (long)E_TOT + e);
  atomicAdd(&hist[dst], 1);
}

__global__ __launch_bounds__(256) void scan_kernel(
    const int* __restrict__ hist, int* __restrict__ rowptr)
{
  __shared__ int part[256];
  int tid = threadIdx.x;
  int base = tid * 40;
  int s = 0;
  for (int i = 0; i < 40; ++i) { int idx = base + i; if (idx < N_NODES) s += hist[idx]; }
  part[tid] = s;
  __syncthreads();
  for (int off = 1; off < 256; off <<= 1) {
    int v = (tid >= off) ? part[tid - off] : 0;
    __syncthreads();
    part[tid] += v;
    __syncthreads();
  }
  int run = (tid > 0) ? part[tid - 1] : 0;
  for (int i = 0; i < 40; ++i) {
    int idx = base + i;
    if (idx < N_NODES) { rowptr[idx] = run; run += hist[idx]; }
  }
  if (tid == 255) rowptr[N_NODES] = run;
}

__global__ __launch_bounds__(256) void permute_kernel(
    const void* __restrict__ edge_index, const int* __restrict__ flags,
    const int* __restrict__ rowptr, int* __restrict__ fill,
    int* __restrict__ perm, int* __restrict__ psrc)
{
  const int i64m = flags[1];
  int e = blockIdx.x * 256 + threadIdx.x;
  int dst = get_ei(edge_index, i64m, (long)E_TOT + e);
  int src = get_ei(edge_index, i64m, e);
  int pos = rowptr[dst] + atomicAdd(&fill[dst], 1);
  perm[pos] = e; psrc[pos] = src;
}

// ---------------------------------------------------------------------------
// prep: Wbig^T[o][k<672]: k<320 -> ws_w row k (src ns + edge_s);
//       320..387 -> rows 576..643 (vn); 388..415 -> 0; 416..671 -> rows
//       320..575 (dst ns, i.e. r = k-96). Block 672: whv4 = wh[32:36]@wv.
// ---------------------------------------------------------------------------
__global__ __launch_bounds__(256) void prep_kernel(
    const void* __restrict__ ws_w, const void* __restrict__ wh,
    const void* __restrict__ wv, const int* __restrict__ flags,
    short* __restrict__ Wbig, float* __restrict__ whv4)
{
  const int f32m = flags[0];
  int b = blockIdx.x, tid = threadIdx.x;
  if (b < 672) {
    int flat = b * 256 + tid;           // = o*672 + k
    int o = flat / 672, k = flat % 672;
    short v = 0;
    if (k < 320)      v = f2bf(ldin(ws_w, f32m, (long)k * 256 + o));
    else if (k < 388) v = f2bf(ldin(ws_w, f32m, (long)(576 + k - 320) * 256 + o));
    else if (k >= 416) v = f2bf(ldin(ws_w, f32m, (long)(k - 96) * 256 + o));
    Wbig[flat] = v;
  } else if (tid < 128) {
    int q = tid / 32, c = tid % 32;
    float acc = 0.f;
    for (int h = 0; h < 68; ++h)
      acc += ldin(wh, f32m, (32 + q) * 68 + h) * ldin(wv, f32m, h * 32 + c);
    whv4[tid] = acc;
  }
}

__global__ __launch_bounds__(256) void nsconv_kernel(
    const void* __restrict__ node_s, const int* __restrict__ flags,
    short* __restrict__ ns_bf)
{
  const int f32m = flags[0];
  int i = blockIdx.x * 256 + threadIdx.x;
  ns_bf[i] = f2bf(ldin(node_s, f32m, i));
}

// ---------------------------------------------------------------------------
// node_pre: per 4 nodes — PQ row (480 shorts): P' h-major [h*4+d] (272 incl
// pad d=3), then Q [d*68+h] (204), then 4 pad. QV bf16 unchanged.
// ---------------------------------------------------------------------------
__global__ __launch_bounds__(256) void node_pre(
    const void* __restrict__ node_v, const void* __restrict__ wh,
    const void* __restrict__ wv, const int* __restrict__ flags,
    short* __restrict__ PQ, short* __restrict__ QV)
{
  const int f32m = flags[0];
  int n0 = blockIdx.x * 4, tid = threadIdx.x;
  __shared__ float nv[4][96];
  __shared__ float pq[4][408];
  for (int i = tid; i < 4 * 96; i += 256) nv[i / 96][i % 96] = ldin(node_v, f32m, (long)n0 * 96 + i);
  __syncthreads();
  for (int o = tid; o < 4 * 408; o += 256) {
    int i = o / 408, r0 = o % 408;
    int part = r0 / 204, r = r0 % 204, d = r / 68, h = r % 68;
    int cbase = part ? 36 : 0;
    float acc = 0.f;
#pragma unroll
    for (int c = 0; c < 32; ++c)
      acc += nv[i][c * 3 + d] * ldin(wh, f32m, (cbase + c) * 68 + h);
    pq[i][r0] = acc;
  }
  __syncthreads();
  for (int o = tid; o < 4 * 480; o += 256) {
    int i = o / 480, k = o % 480;
    short v = 0;
    if (k < 272) {
      int h = k >> 2, d = k & 3;
      if (d < 3) v = f2bf(pq[i][d * 68 + h]);
    } else if (k < 476) {
      v = f2bf(pq[i][204 + (k - 272)]);
    }
    PQ[(long)(n0 + i) * 480 + k] = v;
  }
  for (int o = tid; o < 4 * 96; o += 256) {
    int i = o / 96, r = o % 96, d = r / 32, c = r % 32;
    float acc = 0.f;
    for (int h = 0; h < 68; ++h)
      acc += pq[i][204 + d * 68 + h] * ldin(wv, f32m, h * 32 + c);
    QV[(long)(n0 + i) * 96 + r] = f2bf(acc);
  }
}

// ---------------------------------------------------------------------------
// edge_wave: ONE WAVE PER DST NODE. No LDS, no barriers. Lane l owns:
//   scalar agg channels 4l..4l+3 (ANS), edge_s channel l (AES),
//   vector channel h=l (vh/norm/AP/AVN); lanes 0..3 also own h=64..67.
// All per-edge work is lane-local thanks to the h-major P' layout.
// ---------------------------------------------------------------------------
template <int F32M>
__device__ __forceinline__ void edge_body(
    const void* __restrict__ edge_v, const void* __restrict__ edge_s,
    const void* __restrict__ wh,
    const int* __restrict__ rowptr, const int* __restrict__ perm,
    const int* __restrict__ psrc, const short* __restrict__ PQ,
    const short* __restrict__ nsb,
    short* __restrict__ ANSb, short* __restrict__ EAb,
    float* __restrict__ AP, float* __restrict__ AEV)
{
  const int lane = threadIdx.x & 63;
  const int n = blockIdx.x * 4 + (threadIdx.x >> 6);
  const int beg = rowptr[n], deg = rowptr[n + 1] - beg;
  const bool has2 = (lane < 4);
  const int h2 = 64 + lane;
  // per-h weight columns wh[32+c][h]
  const float w4a0 = ldin(wh, F32M, 32 * 68 + lane);
  const float w4a1 = ldin(wh, F32M, 33 * 68 + lane);
  const float w4a2 = ldin(wh, F32M, 34 * 68 + lane);
  const float w4a3 = ldin(wh, F32M, 35 * 68 + lane);
  const float w4b0 = has2 ? ldin(wh, F32M, 32 * 68 + h2) : 0.f;
  const float w4b1 = has2 ? ldin(wh, F32M, 33 * 68 + h2) : 0.f;
  const float w4b2 = has2 ? ldin(wh, F32M, 34 * 68 + h2) : 0.f;
  const float w4b3 = has2 ? ldin(wh, F32M, 35 * 68 + h2) : 0.f;
  // Q[dst] channels for this lane's h
  const short* pqQ = PQ + (long)n * 480 + 272;
  const float qa0 = bf(pqQ[0 * 68 + lane]);
  const float qa1 = bf(pqQ[1 * 68 + lane]);
  const float qa2 = bf(pqQ[2 * 68 + lane]);
  const float qb0 = has2 ? bf(pqQ[0 * 68 + h2]) : 0.f;
  const float qb1 = has2 ? bf(pqQ[1 * 68 + h2]) : 0.f;
  const float qb2 = has2 ? bf(pqQ[2 * 68 + h2]) : 0.f;
  float an0 = 0.f, an1 = 0.f, an2 = 0.f, an3 = 0.f;
  float ap0 = 0.f, ap1 = 0.f, ap2 = 0.f;
  float bq0 = 0.f, bq1 = 0.f, bq2 = 0.f;
  float avna = 0.f, avnb = 0.f, aes = 0.f, aev = 0.f;
  for (int e = 0; e < deg; ++e) {
    const int sv  = psrc[beg + e];   // wave-uniform broadcast loads
    const int eid = perm[beg + e];
    float ev0, ev1, ev2, ev3, ev4, ev5, ev6, ev7, ev8, ev9, evA, evB;
    if (F32M) {
      const float* evp = (const float*)edge_v + (long)eid * 12;
      f32x4 a = *(const f32x4*)evp;
      f32x4 b = *(const f32x4*)(evp + 4);
      f32x4 c = *(const f32x4*)(evp + 8);
      ev0 = a.x; ev1 = a.y; ev2 = a.z; ev3 = a.w;
      ev4 = b.x; ev5 = b.y; ev6 = b.z; ev7 = b.w;
      ev8 = c.x; ev9 = c.y; evA = c.z; evB = c.w;
    } else {
      const short* evp = (const short*)edge_v + (long)eid * 12;
      s16x4 a = *(const s16x4*)evp;
      s16x4 b = *(const s16x4*)(evp + 4);
      s16x4 c = *(const s16x4*)(evp + 8);
      ev0 = bf(a.x); ev1 = bf(a.y); ev2 = bf(a.z); ev3 = bf(a.w);
      ev4 = bf(b.x); ev5 = bf(b.y); ev6 = bf(b.z); ev7 = bf(b.w);
      ev8 = bf(c.x); ev9 = bf(c.y); evA = bf(c.z); evB = bf(c.w);
    }
    const short* ps = PQ + (long)sv * 480;
    s16x4 pv = *(const s16x4*)(ps + lane * 4);
    const float pa0 = bf(pv.x), pa1 = bf(pv.y), pa2 = bf(pv.z);
    s16x4 nvv = *(const s16x4*)(nsb + (long)sv * 256 + lane * 4);
    an0 += bf(nvv.x); an1 += bf(nvv.y); an2 += bf(nvv.z); an3 += bf(nvv.w);
    aes += ldin(edge_s, F32M, (long)eid * 64 + lane);
    if (lane < 12) aev += ldin(edge_v, F32M, (long)eid * 12 + lane);
    // vh and norm, lane-local (h = lane)
    float v0 = pa0 + qa0 + ev0 * w4a0 + ev3 * w4a1 + ev6 * w4a2 + ev9 * w4a3;
    float v1 = pa1 + qa1 + ev1 * w4a0 + ev4 * w4a1 + ev7 * w4a2 + evA * w4a3;
    float v2 = pa2 + qa2 + ev2 * w4a0 + ev5 * w4a1 + ev8 * w4a2 + evB * w4a3;
    avna += sqrtf(fmaxf(v0 * v0 + v1 * v1 + v2 * v2, 1e-8f));
    ap0 += pa0; ap1 += pa1; ap2 += pa2;
    if (has2) {  // h = 64..67 on lanes 0..3
      s16x4 p2 = *(const s16x4*)(ps + h2 * 4);
      const float pb0 = bf(p2.x), pb1 = bf(p2.y), pb2 = bf(p2.z);
      float u0 = pb0 + qb0 + ev0 * w4b0 + ev3 * w4b1 + ev6 * w4b2 + ev9 * w4b3;
      float u1 = pb1 + qb1 + ev1 * w4b0 + ev4 * w4b1 + ev7 * w4b2 + evA * w4b3;
      float u2 = pb2 + qb2 + ev2 * w4b0 + ev5 * w4b1 + ev8 * w4b2 + evB * w4b3;
      avnb += sqrtf(fmaxf(u0 * u0 + u1 * u1 + u2 * u2, 1e-8f));
      bq0 += pb0; bq1 += pb1; bq2 += pb2;
    }
  }
  const float inv = 1.f / fmaxf((float)deg, 1.f);
  s16x4 av;
  av.x = f2bf(an0 * inv); av.y = f2bf(an1 * inv);
  av.z = f2bf(an2 * inv); av.w = f2bf(an3 * inv);
  *(s16x4*)(ANSb + (long)n * 256 + lane * 4) = av;
  EAb[(long)n * 160 + lane] = f2bf(aes * inv);
  EAb[(long)n * 160 + 64 + lane] = f2bf(avna * inv);
  if (has2) EAb[(long)n * 160 + 128 + lane] = f2bf(avnb * inv);
  if (lane >= 4 && lane < 32) EAb[(long)n * 160 + 128 + lane] = 0;
  float* app = AP + (long)n * 204 + lane * 3;
  app[0] = ap0; app[1] = ap1; app[2] = ap2;
  if (has2) {
    float* apb = AP + (long)n * 204 + h2 * 3;
    apb[0] = bq0; apb[1] = bq1; apb[2] = bq2;
  }
  if (lane < 12) AEV[(long)n * 12 + lane] = aev;
}

__global__ __launch_bounds__(256) void edge_wave(
    const void* __restrict__ edge_v, const void* __restrict__ edge_s,
    const void* __restrict__ wh, const int* __restrict__ flags,
    const int* __restrict__ rowptr, const int* __restrict__ perm,
    const int* __restrict__ psrc, const short* __restrict__ PQ,
    const short* __restrict__ nsb,
    short* __restrict__ ANSb, short* __restrict__ EAb,
    float* __restrict__ AP, float* __restrict__ AEV)
{
  if (flags[0])
    edge_body<1>(edge_v, edge_s, wh, rowptr, perm, psrc, PQ, nsb,
                 ANSb, EAb, AP, AEV);
  else
    edge_body<0>(edge_v, edge_s, wh, rowptr, perm, psrc, PQ, nsb,
                 ANSb, EAb, AP, AEV);
}

// ---------------------------------------------------------------------------
// node_gemm: NodeS[n] = [ANS/deg | AES/deg|AVN/deg | ns] @ Wbig
// ([N,672]@[672,256]); 64 rows/block, 21 K-slabs, direct f32 stores.
// ---------------------------------------------------------------------------
__global__ __launch_bounds__(256) void node_gemm(
    const short* __restrict__ ANSb, const short* __restrict__ EAb,
    const short* __restrict__ nsb, const short* __restrict__ Wbig,
    float* __restrict__ NodeS)
{
  __shared__ __align__(16) short Xs[64 * 40];
  __shared__ __align__(16) short Ws[256 * 40];
  const int tid = threadIdx.x;
  const int n0 = blockIdx.x * 64;
  const int lane = tid & 63, wave = tid >> 6;
  const int frow = lane & 15, fk = (lane >> 4) * 8, q = lane >> 4;
  f32x4 acc[4][4];
#pragma unroll
  for (int ri = 0; ri < 4; ++ri)
#pragma unroll
    for (int ci = 0; ci < 4; ++ci)
      acc[ri][ci] = (f32x4){0.f, 0.f, 0.f, 0.f};
  const int se = tid >> 2, sq = tid & 3;
  const int rn = min(n0 + se, N_NODES - 1);
  for (int s = 0; s < 21; ++s) {
    short8 xv;
    if (s < 8)       xv = *(const short8*)&ANSb[(long)rn * 256 + s * 32 + sq * 8];
    else if (s < 13) xv = *(const short8*)&EAb[(long)rn * 160 + (s - 8) * 32 + sq * 8];
    else             xv = *(const short8*)&nsb[(long)rn * 256 + (s - 13) * 32 + sq * 8];
    *(short8*)&Xs[se * 40 + sq * 8] = xv;
#pragma unroll
    for (int it = 0; it < 4; ++it) {
      int flat = it * 256 + tid;
      int nn = flat >> 2, qq = flat & 3;
      *(short8*)&Ws[nn * 40 + qq * 8] = *(const short8*)&Wbig[nn * 672 + s * 32 + qq * 8];
    }
    __syncthreads();
    short8 a[4];
#pragma unroll
    for (int ri = 0; ri < 4; ++ri)
      a[ri] = *(const short8*)&Xs[(ri * 16 + frow) * 40 + fk];
#pragma unroll
    for (int ci = 0; ci < 4; ++ci) {
      int nn = wave * 64 + ci * 16 + frow;
      short8 b = *(const short8*)&Ws[nn * 40 + fk];
#pragma unroll
      for (int ri = 0; ri < 4; ++ri)
        acc[ri][ci] = __builtin_amdgcn_mfma_f32_16x16x32_bf16(a[ri], b, acc[ri][ci], 0, 0, 0);
    }
    __syncthreads();
  }
#pragma unroll
  for (int ri = 0; ri < 4; ++ri)
#pragma unroll
    for (int rr = 0; rr < 4; ++rr) {
      int row = n0 + ri * 16 + q * 4 + rr;
      if (row < N_NODES) {
#pragma unroll
        for (int ci = 0; ci < 4; ++ci) {
          int col = wave * 64 + ci * 16 + (lane & 15);
          NodeS[(long)row * 256 + col] = acc[ri][ci][rr];
        }
      }
    }
}

// ---------------------------------------------------------------------------
// nodev: agg_v[n] = AP[n] @ wv + AEV[n] @ whv4   (4 nodes/block)
// AP layout is [h*3+d].
// ---------------------------------------------------------------------------
__global__ __launch_bounds__(256) void nodev_kernel(
    const float* __restrict__ AP, const float* __restrict__ AEV,
    const void* __restrict__ wv, const float* __restrict__ whv4,
    const int* __restrict__ flags, float* __restrict__ agg_v)
{
  const int f32m = flags[0];
  int n0 = blockIdx.x * 4, tid = threadIdx.x;
  __shared__ float wvs[68 * 32];
  __shared__ float wh4s[128];
  __shared__ float APs[4][204];
  __shared__ float AEVs[4][12];
  for (int i = tid; i < 2176; i += 256) wvs[i] = ldin(wv, f32m, i);
  if (tid < 128) wh4s[tid] = whv4[tid];
  for (int i = tid; i < 816; i += 256) APs[i / 204][i % 204] = AP[(long)n0 * 204 + i];
  if (tid < 48) AEVs[tid / 12][tid % 12] = AEV[(long)n0 * 12 + tid];
  __syncthreads();
  for (int o = tid; o < 384; o += 256) {
    int i = o / 96, r = o % 96, c = r / 3, d = r % 3;
    float acc = AEVs[i][d] * wh4s[c] + AEVs[i][3 + d] * wh4s[32 + c]
              + AEVs[i][6 + d] * wh4s[64 + c] + AEVs[i][9 + d] * wh4s[96 + c];
    for (int h = 0; h < 68; ++h)
      acc += APs[i][h * 3 + d] * wvs[h * 32 + c];
    agg_v[(long)(n0 + i) * 96 + r] = acc;
  }
}

// ---------------------------------------------------------------------------
__global__ __launch_bounds__(256) void finalize(
    const float* __restrict__ NodeS, const float* __restrict__ agg_v,
    const int* __restrict__ rowptr, const short* __restrict__ QV,
    const void* __restrict__ ws_b, const int* __restrict__ flags,
    void* __restrict__ out)
{
  const int f32m = flags[0];
  int flat = blockIdx.x * 256 + threadIdx.x;   // N*352 exact
  int n = flat / 352, j = flat % 352;
  int deg = rowptr[n + 1] - rowptr[n];
  float v;
  if (j < 256) {
    v = (deg > 0) ? (NodeS[(long)n * 256 + j] + ldin(ws_b, f32m, j)) : 0.f;
  } else {
    int m = j - 256, ch = m / 3, d = m % 3;
    float inv = 1.f / fmaxf((float)deg, 1.f);
    v = agg_v[(long)n * 96 + m] * inv;
    if (deg > 0) v += bf(QV[(long)n * 96 + d * 32 + ch]);
  }
  if (f32m) ((float*)out)[flat] = v;
  else      ((__hip_bfloat16*)out)[flat] = __float2bfloat16(v);
}

extern "C" void kernel_launch(void* const* d_in, const int* in_sizes, int n_in,
                              void* d_out, int out_size, void* d_ws, size_t ws_size,
                              hipStream_t stream) {
  const void* node_s = d_in[0];
  const void* node_v = d_in[1];
  const void* edge_s = d_in[2];
  const void* edge_v = d_in[3];
  const void* wh     = d_in[4];
  const void* ws_w   = d_in[5];
  const void* ws_b   = d_in[6];
  const void* wv     = d_in[7];
  const void* edge_index = d_in[8];

  char* ws = (char*)d_ws;
  int*   hist  = (int*)(ws + HIST_OFF);
  int*   fill  = (int*)(ws + FILL_OFF);
  int*   rowptr= (int*)(ws + ROWPTR_OFF);
  int*   perm  = (int*)(ws + PERM_OFF);
  int*   psrc  = (int*)(ws + PSRC_OFF);
  short* PQ    = (short*)(ws + PQ_OFF);
  short* QV    = (short*)(ws + QV_OFF);
  float* whv4  = (float*)(ws + WHV4_OFF);
  short* Wbig  = (short*)(ws + WBIG_OFF);
  short* ns_bf = (short*)(ws + NSBF_OFF);
  short* ANSb  = (short*)(ws + ANSB_OFF);
  short* EAb   = (short*)(ws + EAB_OFF);
  float* AP    = (float*)(ws + AP_OFF);
  float* AEV   = (float*)(ws + AEV_OFF);
  float* NodeS = (float*)(ws + NODES_OFF);
  float* agg_v = (float*)(ws + AGGV_OFF);
  int*   flags = (int*)(ws + FLAGS_OFF);

  hipMemsetAsync(d_ws, 0, ZERO_BYTES, stream);
  detect_kernel<<<1, 256, 0, stream>>>((const unsigned short*)node_s,
                                       (const int*)edge_index, flags);
  hist_kernel<<<1250, 256, 0, stream>>>(edge_index, flags, hist);
  scan_kernel<<<1, 256, 0, stream>>>(hist, rowptr);
  permute_kernel<<<1250, 256, 0, stream>>>(edge_index, flags, rowptr, fill,
                                           perm, psrc);
  prep_kernel<<<673, 256, 0, stream>>>(ws_w, wh, wv, flags, Wbig, whv4);
  nsconv_kernel<<<10000, 256, 0, stream>>>(node_s, flags, ns_bf);
  node_pre<<<2500, 256, 0, stream>>>(node_v, wh, wv, flags, PQ, QV);
  edge_wave<<<2500, 256, 0, stream>>>(edge_v, edge_s, wh, flags, rowptr,
                                      perm, psrc, PQ, ns_bf,
                                      ANSb, EAb, AP, AEV);
  node_gemm<<<157, 256, 0, stream>>>(ANSb, EAb, ns_bf, Wbig, NodeS);
  nodev_kernel<<<2500, 256, 0, stream>>>(AP, AEV, wv, whv4, flags, agg_v);
  finalize<<<13750, 256, 0, stream>>>(NodeS, agg_v, rowptr, QV, ws_b,
                                      flags, d_out);
}

// Round 5
// 466.178 us; speedup vs baseline: 1.0872x; 1.0474x over previous
//
#include <hip/hip_runtime.h>
#include <hip/hip_bf16.h>

#define N_NODES 10000
#define E_TOT   320000

typedef __attribute__((ext_vector_type(8))) short short8;
typedef __attribute__((ext_vector_type(4))) short s16x4;
typedef __attribute__((ext_vector_type(4))) float f32x4;

// ---- workspace byte offsets (16B-aligned; total ~40.5 MB) ----
#define HIST_OFF    0u            // N int (zeroed)
#define FILL_OFF    40000u        // N int (zeroed)
#define ZERO_BYTES  80000u        // memset [0, here) -- only the sort counters!
#define ROWPTR_OFF  80000u        // (N+1) int (fully written by scan)
#define PERM_OFF    120064u       // E int
#define PSRC_OFF    1400064u      // E int
#define PQ_OFF      2680064u      // N*480 shorts: P'(272, h*4+d pad) | Q(204, d*68+h) | pad4
#define QV_OFF      12280064u     // N*96 bf16
#define WHV4_OFF    14200064u     // 128 f32
#define WBIG_OFF    14200576u     // 256*672 bf16 = 344,064  mega scalar GEMM W^T
#define NSBF_OFF    14544640u     // N*256 bf16
#define ANSB_OFF    19664640u     // N*256 bf16  (sum ns[src])/deg
#define EAB_OFF     24784640u     // N*160 bf16  [AES(64)|AVN(68)|pad(28)]/deg
#define AP_OFF      27984640u     // N*204 f32   sum P[src], layout [h*3+d]
#define AEV_OFF     36144640u     // N*12 f32    sum edge_v
#define AGGV_OFF    36624640u     // (unused now; kept for layout stability)
#define FLAGS_OFF   40464640u     // 2 ints
// NodeS (N*256 f32 = 10.24MB) aliases [PERM_OFF, ...) -- perm/psrc/PQ are
// dead by the time node_gemm writes it; rowptr (ends 120004) untouched.
#define NODES_OFF   120064u

union BfS { __hip_bfloat16 h; short s; };
__device__ __forceinline__ short f2bf(float x) { BfS u; u.h = __float2bfloat16(x); return u.s; }
__device__ __forceinline__ float bf(short x) { BfS u; u.s = x; return __bfloat162float(u.h); }
__device__ __forceinline__ float ldin(const void* p, int f32m, long i) {
  return f32m ? ((const float*)p)[i] : __bfloat162float(((const __hip_bfloat16*)p)[i]);
}
__device__ __forceinline__ int get_ei(const void* p, int i64m, long i) {
  return i64m ? (int)(((const long long*)p)[i]) : ((const int*)p)[i];
}

// ---------------------------------------------------------------------------
__global__ __launch_bounds__(256) void detect_kernel(
    const unsigned short* __restrict__ ns_u16,
    const int* __restrict__ ei_i32, int* __restrict__ flags)
{
  __shared__ int cf, ci;
  if (threadIdx.x == 0) { cf = 0; ci = 0; }
  __syncthreads();
  int c1 = 0;
  for (int i = threadIdx.x; i < 8192; i += 256) {
    unsigned e = (ns_u16[2 * i] >> 7) & 0xFF;
    if (e < 100 || e > 140) c1++;
  }
  int c2 = 0;
  for (int i = threadIdx.x; i < 4096; i += 256)
    if (ei_i32[2 * i + 1] != 0) c2++;
  atomicAdd(&cf, c1); atomicAdd(&ci, c2);
  __syncthreads();
  if (threadIdx.x == 0) {
    flags[0] = (cf > 512) ? 1 : 0;   // 1 => f32 inputs
    flags[1] = (ci < 100) ? 1 : 0;   // 1 => int64 edge_index
  }
}

// ---------------------------------------------------------------------------
__global__ __launch_bounds__(256) void hist_kernel(
    const void* __restrict__ edge_index, const int* __restrict__ flags,
    int* __restrict__ hist)
{
  const int i64m = flags[1];
  int e = blockIdx.x * 256 + threadIdx.x;
  int dst = get_ei(edge_index, i64m, (long)E_TOT + e);
  atomicAdd(&hist[dst], 1);
}

__global__ __launch_bounds__(256) void scan_kernel(
    const int* __restrict__ hist, int* __restrict__ rowptr)
{
  __shared__ int part[256];
  int tid = threadIdx.x;
  int base = tid * 40;
  int s = 0;
  for (int i = 0; i < 40; ++i) { int idx = base + i; if (idx < N_NODES) s += hist[idx]; }
  part[tid] = s;
  __syncthreads();
  for (int off = 1; off < 256; off <<= 1) {
    int v = (tid >= off) ? part[tid - off] : 0;
    __syncthreads();
    part[tid] += v;
    __syncthreads();
  }
  int run = (tid > 0) ? part[tid - 1] : 0;
  for (int i = 0; i < 40; ++i) {
    int idx = base + i;
    if (idx < N_NODES) { rowptr[idx] = run; run += hist[idx]; }
  }
  if (tid == 255) rowptr[N_NODES] = run;
}

__global__ __launch_bounds__(256) void permute_kernel(
    const void* __restrict__ edge_index, const int* __restrict__ flags,
    const int* __restrict__ rowptr, int* __restrict__ fill,
    int* __restrict__ perm, int* __restrict__ psrc)
{
  const int i64m = flags[1];
  int e = blockIdx.x * 256 + threadIdx.x;
  int dst = get_ei(edge_index, i64m, (long)E_TOT + e);
  int src = get_ei(edge_index, i64m, e);
  int pos = rowptr[dst] + atomicAdd(&fill[dst], 1);
  perm[pos] = e; psrc[pos] = src;
}

// ---------------------------------------------------------------------------
// prep: Wbig^T[o][k<672]: k<320 -> ws_w row k (src ns + edge_s);
//       320..387 -> rows 576..643 (vn); 388..415 -> 0; 416..671 -> rows
//       320..575 (dst ns, i.e. r = k-96). Block 672: whv4 = wh[32:36]@wv.
// ---------------------------------------------------------------------------
__global__ __launch_bounds__(256) void prep_kernel(
    const void* __restrict__ ws_w, const void* __restrict__ wh,
    const void* __restrict__ wv, const int* __restrict__ flags,
    short* __restrict__ Wbig, float* __restrict__ whv4)
{
  const int f32m = flags[0];
  int b = blockIdx.x, tid = threadIdx.x;
  if (b < 672) {
    int flat = b * 256 + tid;           // = o*672 + k
    int o = flat / 672, k = flat % 672;
    short v = 0;
    if (k < 320)      v = f2bf(ldin(ws_w, f32m, (long)k * 256 + o));
    else if (k < 388) v = f2bf(ldin(ws_w, f32m, (long)(576 + k - 320) * 256 + o));
    else if (k >= 416) v = f2bf(ldin(ws_w, f32m, (long)(k - 96) * 256 + o));
    Wbig[flat] = v;
  } else if (tid < 128) {
    int q = tid / 32, c = tid % 32;
    float acc = 0.f;
    for (int h = 0; h < 68; ++h)
      acc += ldin(wh, f32m, (32 + q) * 68 + h) * ldin(wv, f32m, h * 32 + c);
    whv4[tid] = acc;
  }
}

// ---------------------------------------------------------------------------
// node_pre: per 4 nodes — PQ row (480 shorts): P' h-major [h*4+d] (272 incl
// pad d=3), then Q [d*68+h] (204), then 4 pad. QV bf16. Also converts this
// block's 4 node_s rows to bf16 (fused former nsconv kernel).
// ---------------------------------------------------------------------------
__global__ __launch_bounds__(256) void node_pre(
    const void* __restrict__ node_v, const void* __restrict__ wh,
    const void* __restrict__ wv, const void* __restrict__ node_s,
    const int* __restrict__ flags,
    short* __restrict__ PQ, short* __restrict__ QV, short* __restrict__ ns_bf)
{
  const int f32m = flags[0];
  int n0 = blockIdx.x * 4, tid = threadIdx.x;
  __shared__ float nv[4][96];
  __shared__ float pq[4][408];
  for (int i = tid; i < 4 * 96; i += 256) nv[i / 96][i % 96] = ldin(node_v, f32m, (long)n0 * 96 + i);
  // fused nsconv: 4 nodes x 256 channels
  for (int i = tid; i < 1024; i += 256)
    ns_bf[(long)n0 * 256 + i] = f2bf(ldin(node_s, f32m, (long)n0 * 256 + i));
  __syncthreads();
  for (int o = tid; o < 4 * 408; o += 256) {
    int i = o / 408, r0 = o % 408;
    int part = r0 / 204, r = r0 % 204, d = r / 68, h = r % 68;
    int cbase = part ? 36 : 0;
    float acc = 0.f;
#pragma unroll
    for (int c = 0; c < 32; ++c)
      acc += nv[i][c * 3 + d] * ldin(wh, f32m, (cbase + c) * 68 + h);
    pq[i][r0] = acc;
  }
  __syncthreads();
  for (int o = tid; o < 4 * 480; o += 256) {
    int i = o / 480, k = o % 480;
    short v = 0;
    if (k < 272) {
      int h = k >> 2, d = k & 3;
      if (d < 3) v = f2bf(pq[i][d * 68 + h]);
    } else if (k < 476) {
      v = f2bf(pq[i][204 + (k - 272)]);
    }
    PQ[(long)(n0 + i) * 480 + k] = v;
  }
  for (int o = tid; o < 4 * 96; o += 256) {
    int i = o / 96, r = o % 96, d = r / 32, c = r % 32;
    float acc = 0.f;
    for (int h = 0; h < 68; ++h)
      acc += pq[i][204 + d * 68 + h] * ldin(wv, f32m, h * 32 + c);
    QV[(long)(n0 + i) * 96 + r] = f2bf(acc);
  }
}

// ---------------------------------------------------------------------------
// edge_block: ONE BLOCK (4 waves) PER DST NODE. Wave w takes edges
// e = w, w+4, ... (stride 4) -> 4x wave-level parallelism, ~8-edge serial
// chains, index prefetch. Lane-local h-major P' layout. One barrier +
// f32 LDS reduce across the 4 waves.
// ---------------------------------------------------------------------------
template <int F32M>
__device__ __forceinline__ void edge_body(
    const void* __restrict__ edge_v, const void* __restrict__ edge_s,
    const void* __restrict__ wh,
    const int* __restrict__ rowptr, const int* __restrict__ perm,
    const int* __restrict__ psrc, const short* __restrict__ PQ,
    const short* __restrict__ nsb,
    short* __restrict__ ANSb, short* __restrict__ EAb,
    float* __restrict__ AP, float* __restrict__ AEV)
{
  const int tid = threadIdx.x;
  const int lane = tid & 63, w = tid >> 6;
  const int n = blockIdx.x;
  const int beg = rowptr[n], deg = rowptr[n + 1] - beg;
  const bool has2 = (lane < 4);
  const int h2 = 64 + lane;
  // per-h weight columns wh[32+c][h]
  const float w4a0 = ldin(wh, F32M, 32 * 68 + lane);
  const float w4a1 = ldin(wh, F32M, 33 * 68 + lane);
  const float w4a2 = ldin(wh, F32M, 34 * 68 + lane);
  const float w4a3 = ldin(wh, F32M, 35 * 68 + lane);
  const float w4b0 = has2 ? ldin(wh, F32M, 32 * 68 + h2) : 0.f;
  const float w4b1 = has2 ? ldin(wh, F32M, 33 * 68 + h2) : 0.f;
  const float w4b2 = has2 ? ldin(wh, F32M, 34 * 68 + h2) : 0.f;
  const float w4b3 = has2 ? ldin(wh, F32M, 35 * 68 + h2) : 0.f;
  // Q[dst] channels for this lane's h
  const short* pqQ = PQ + (long)n * 480 + 272;
  const float qa0 = bf(pqQ[0 * 68 + lane]);
  const float qa1 = bf(pqQ[1 * 68 + lane]);
  const float qa2 = bf(pqQ[2 * 68 + lane]);
  const float qb0 = has2 ? bf(pqQ[0 * 68 + h2]) : 0.f;
  const float qb1 = has2 ? bf(pqQ[1 * 68 + h2]) : 0.f;
  const float qb2 = has2 ? bf(pqQ[2 * 68 + h2]) : 0.f;
  float an0 = 0.f, an1 = 0.f, an2 = 0.f, an3 = 0.f;
  float ap0 = 0.f, ap1 = 0.f, ap2 = 0.f;
  float bq0 = 0.f, bq1 = 0.f, bq2 = 0.f;
  float avna = 0.f, avnb = 0.f, aes = 0.f, aev = 0.f;
  int e = w;
  int sv = 0, eid = 0;
  if (e < deg) { sv = psrc[beg + e]; eid = perm[beg + e]; }
  while (e < deg) {
    // prefetch next iteration's indices (overlap index->gather dependence)
    int en = e + 4, svn = 0, eidn = 0;
    if (en < deg) { svn = psrc[beg + en]; eidn = perm[beg + en]; }
    float ev0, ev1, ev2, ev3, ev4, ev5, ev6, ev7, ev8, ev9, evA, evB;
    if (F32M) {
      const float* evp = (const float*)edge_v + (long)eid * 12;
      f32x4 a = *(const f32x4*)evp;
      f32x4 b = *(const f32x4*)(evp + 4);
      f32x4 c = *(const f32x4*)(evp + 8);
      ev0 = a.x; ev1 = a.y; ev2 = a.z; ev3 = a.w;
      ev4 = b.x; ev5 = b.y; ev6 = b.z; ev7 = b.w;
      ev8 = c.x; ev9 = c.y; evA = c.z; evB = c.w;
    } else {
      const short* evp = (const short*)edge_v + (long)eid * 12;
      s16x4 a = *(const s16x4*)evp;
      s16x4 b = *(const s16x4*)(evp + 4);
      s16x4 c = *(const s16x4*)(evp + 8);
      ev0 = bf(a.x); ev1 = bf(a.y); ev2 = bf(a.z); ev3 = bf(a.w);
      ev4 = bf(b.x); ev5 = bf(b.y); ev6 = bf(b.z); ev7 = bf(b.w);
      ev8 = bf(c.x); ev9 = bf(c.y); evA = bf(c.z); evB = bf(c.w);
    }
    const short* ps = PQ + (long)sv * 480;
    s16x4 pv = *(const s16x4*)(ps + lane * 4);
    const float pa0 = bf(pv.x), pa1 = bf(pv.y), pa2 = bf(pv.z);
    s16x4 nvv = *(const s16x4*)(nsb + (long)sv * 256 + lane * 4);
    an0 += bf(nvv.x); an1 += bf(nvv.y); an2 += bf(nvv.z); an3 += bf(nvv.w);
    aes += ldin(edge_s, F32M, (long)eid * 64 + lane);
    if (lane < 12) aev += ldin(edge_v, F32M, (long)eid * 12 + lane);
    // vh and norm, lane-local (h = lane)
    float v0 = pa0 + qa0 + ev0 * w4a0 + ev3 * w4a1 + ev6 * w4a2 + ev9 * w4a3;
    float v1 = pa1 + qa1 + ev1 * w4a0 + ev4 * w4a1 + ev7 * w4a2 + evA * w4a3;
    float v2 = pa2 + qa2 + ev2 * w4a0 + ev5 * w4a1 + ev8 * w4a2 + evB * w4a3;
    avna += sqrtf(fmaxf(v0 * v0 + v1 * v1 + v2 * v2, 1e-8f));
    ap0 += pa0; ap1 += pa1; ap2 += pa2;
    if (has2) {  // h = 64..67 on lanes 0..3
      s16x4 p2 = *(const s16x4*)(ps + h2 * 4);
      const float pb0 = bf(p2.x), pb1 = bf(p2.y), pb2 = bf(p2.z);
      float u0 = pb0 + qb0 + ev0 * w4b0 + ev3 * w4b1 + ev6 * w4b2 + ev9 * w4b3;
      float u1 = pb1 + qb1 + ev1 * w4b0 + ev4 * w4b1 + ev7 * w4b2 + evA * w4b3;
      float u2 = pb2 + qb2 + ev2 * w4b0 + ev5 * w4b1 + ev8 * w4b2 + evB * w4b3;
      avnb += sqrtf(fmaxf(u0 * u0 + u1 * u1 + u2 * u2, 1e-8f));
      bq0 += pb0; bq1 += pb1; bq2 += pb2;
    }
    e = en; sv = svn; eid = eidn;
  }
  // ---- cross-wave f32 reduction in LDS (one barrier) ----
  __shared__ float ansL[4][256];
  __shared__ float apL[4][204];
  __shared__ float avnL[4][132];   // [0..63]=avna(h=lane), [64..67]=avnb(lanes 0..3)
  __shared__ float aesL[4][64];
  __shared__ float aevL[4][12];
  ansL[w][lane * 4 + 0] = an0; ansL[w][lane * 4 + 1] = an1;
  ansL[w][lane * 4 + 2] = an2; ansL[w][lane * 4 + 3] = an3;
  apL[w][lane * 3 + 0] = ap0; apL[w][lane * 3 + 1] = ap1; apL[w][lane * 3 + 2] = ap2;
  if (has2) {
    apL[w][192 + lane * 3 + 0] = bq0;
    apL[w][192 + lane * 3 + 1] = bq1;
    apL[w][192 + lane * 3 + 2] = bq2;
  }
  avnL[w][lane] = avna;
  if (has2) avnL[w][64 + lane] = avnb;
  aesL[w][lane] = aes;
  if (lane < 12) aevL[w][lane] = aev;
  __syncthreads();
  const float inv = 1.f / fmaxf((float)deg, 1.f);
  {
    float s = ansL[0][tid] + ansL[1][tid] + ansL[2][tid] + ansL[3][tid];
    ANSb[(long)n * 256 + tid] = f2bf(s * inv);
  }
  if (tid < 204) {
    float s = apL[0][tid] + apL[1][tid] + apL[2][tid] + apL[3][tid];
    AP[(long)n * 204 + tid] = s;
  } else if (tid < 216) {
    int c = tid - 204;
    float s = aevL[0][c] + aevL[1][c] + aevL[2][c] + aevL[3][c];
    AEV[(long)n * 12 + c] = s;
  }
  if (tid < 64) {
    float s = aesL[0][tid] + aesL[1][tid] + aesL[2][tid] + aesL[3][tid];
    EAb[(long)n * 160 + tid] = f2bf(s * inv);
  } else if (tid < 132) {
    int c = tid - 64;  // AVN channel 0..67; slot c (avna for c<64, avnb 64..67)
    float s = avnL[0][c] + avnL[1][c] + avnL[2][c] + avnL[3][c];
    EAb[(long)n * 160 + 64 + c] = f2bf(s * inv);
  } else if (tid < 160) {
    EAb[(long)n * 160 + tid] = 0;  // pad channels 132..159
  }
}

__global__ __launch_bounds__(256) void edge_block(
    const void* __restrict__ edge_v, const void* __restrict__ edge_s,
    const void* __restrict__ wh, const int* __restrict__ flags,
    const int* __restrict__ rowptr, const int* __restrict__ perm,
    const int* __restrict__ psrc, const short* __restrict__ PQ,
    const short* __restrict__ nsb,
    short* __restrict__ ANSb, short* __restrict__ EAb,
    float* __restrict__ AP, float* __restrict__ AEV)
{
  if (flags[0])
    edge_body<1>(edge_v, edge_s, wh, rowptr, perm, psrc, PQ, nsb,
                 ANSb, EAb, AP, AEV);
  else
    edge_body<0>(edge_v, edge_s, wh, rowptr, perm, psrc, PQ, nsb,
                 ANSb, EAb, AP, AEV);
}

// ---------------------------------------------------------------------------
// node_gemm: NodeS[n] = [ANS/deg | AES/deg|AVN/deg | ns] @ Wbig
// ([N,672]@[672,256]); 64 rows/block, 21 K-slabs, direct f32 stores.
// ---------------------------------------------------------------------------
__global__ __launch_bounds__(256) void node_gemm(
    const short* __restrict__ ANSb, const short* __restrict__ EAb,
    const short* __restrict__ nsb, const short* __restrict__ Wbig,
    float* __restrict__ NodeS)
{
  __shared__ __align__(16) short Xs[64 * 40];
  __shared__ __align__(16) short Ws[256 * 40];
  const int tid = threadIdx.x;
  const int n0 = blockIdx.x * 64;
  const int lane = tid & 63, wave = tid >> 6;
  const int frow = lane & 15, fk = (lane >> 4) * 8, q = lane >> 4;
  f32x4 acc[4][4];
#pragma unroll
  for (int ri = 0; ri < 4; ++ri)
#pragma unroll
    for (int ci = 0; ci < 4; ++ci)
      acc[ri][ci] = (f32x4){0.f, 0.f, 0.f, 0.f};
  const int se = tid >> 2, sq = tid & 3;
  const int rn = min(n0 + se, N_NODES - 1);
  for (int s = 0; s < 21; ++s) {
    short8 xv;
    if (s < 8)       xv = *(const short8*)&ANSb[(long)rn * 256 + s * 32 + sq * 8];
    else if (s < 13) xv = *(const short8*)&EAb[(long)rn * 160 + (s - 8) * 32 + sq * 8];
    else             xv = *(const short8*)&nsb[(long)rn * 256 + (s - 13) * 32 + sq * 8];
    *(short8*)&Xs[se * 40 + sq * 8] = xv;
#pragma unroll
    for (int it = 0; it < 4; ++it) {
      int flat = it * 256 + tid;
      int nn = flat >> 2, qq = flat & 3;
      *(short8*)&Ws[nn * 40 + qq * 8] = *(const short8*)&Wbig[nn * 672 + s * 32 + qq * 8];
    }
    __syncthreads();
    short8 a[4];
#pragma unroll
    for (int ri = 0; ri < 4; ++ri)
      a[ri] = *(const short8*)&Xs[(ri * 16 + frow) * 40 + fk];
#pragma unroll
    for (int ci = 0; ci < 4; ++ci) {
      int nn = wave * 64 + ci * 16 + frow;
      short8 b = *(const short8*)&Ws[nn * 40 + fk];
#pragma unroll
      for (int ri = 0; ri < 4; ++ri)
        acc[ri][ci] = __builtin_amdgcn_mfma_f32_16x16x32_bf16(a[ri], b, acc[ri][ci], 0, 0, 0);
    }
    __syncthreads();
  }
#pragma unroll
  for (int ri = 0; ri < 4; ++ri)
#pragma unroll
    for (int rr = 0; rr < 4; ++rr) {
      int row = n0 + ri * 16 + q * 4 + rr;
      if (row < N_NODES) {
#pragma unroll
        for (int ci = 0; ci < 4; ++ci) {
          int col = wave * 64 + ci * 16 + (lane & 15);
          NodeS[(long)row * 256 + col] = acc[ri][ci][rr];
        }
      }
    }
}

// ---------------------------------------------------------------------------
// final_fuse: per 4 nodes — compute agg_v = AP@wv + AEV@whv4 in LDS (former
// nodev kernel), then write all 4*352 outputs (former finalize kernel).
// ---------------------------------------------------------------------------
__global__ __launch_bounds__(256) void final_fuse(
    const float* __restrict__ NodeS, const float* __restrict__ AP,
    const float* __restrict__ AEV, const void* __restrict__ wv,
    const float* __restrict__ whv4, const int* __restrict__ rowptr,
    const short* __restrict__ QV, const void* __restrict__ ws_b,
    const int* __restrict__ flags, void* __restrict__ out)
{
  const int f32m = flags[0];
  int n0 = blockIdx.x * 4, tid = threadIdx.x;
  __shared__ float wvs[68 * 32];
  __shared__ float wh4s[128];
  __shared__ float APs[4][204];
  __shared__ float AEVs[4][12];
  __shared__ float aggL[4][96];
  for (int i = tid; i < 2176; i += 256) wvs[i] = ldin(wv, f32m, i);
  if (tid < 128) wh4s[tid] = whv4[tid];
  for (int i = tid; i < 816; i += 256) APs[i / 204][i % 204] = AP[(long)n0 * 204 + i];
  if (tid < 48) AEVs[tid / 12][tid % 12] = AEV[(long)n0 * 12 + tid];
  __syncthreads();
  for (int o = tid; o < 384; o += 256) {
    int i = o / 96, r = o % 96, c = r / 3, d = r % 3;
    float acc = AEVs[i][d] * wh4s[c] + AEVs[i][3 + d] * wh4s[32 + c]
              + AEVs[i][6 + d] * wh4s[64 + c] + AEVs[i][9 + d] * wh4s[96 + c];
    for (int h = 0; h < 68; ++h)
      acc += APs[i][h * 3 + d] * wvs[h * 32 + c];
    aggL[i][r] = acc;
  }
  __syncthreads();
  for (int o = tid; o < 1408; o += 256) {
    int i = o / 352, j = o % 352;
    int n = n0 + i;
    int deg = rowptr[n + 1] - rowptr[n];
    float v;
    if (j < 256) {
      v = (deg > 0) ? (NodeS[(long)n * 256 + j] + ldin(ws_b, f32m, j)) : 0.f;
    } else {
      int m = j - 256, ch = m / 3, d = m % 3;
      float inv = 1.f / fmaxf((float)deg, 1.f);
      v = aggL[i][m] * inv;
      if (deg > 0) v += bf(QV[(long)n * 96 + d * 32 + ch]);
    }
    long flat = (long)n * 352 + j;
    if (f32m) ((float*)out)[flat] = v;
    else      ((__hip_bfloat16*)out)[flat] = __float2bfloat16(v);
  }
}

extern "C" void kernel_launch(void* const* d_in, const int* in_sizes, int n_in,
                              void* d_out, int out_size, void* d_ws, size_t ws_size,
                              hipStream_t stream) {
  const void* node_s = d_in[0];
  const void* node_v = d_in[1];
  const void* edge_s = d_in[2];
  const void* edge_v = d_in[3];
  const void* wh     = d_in[4];
  const void* ws_w   = d_in[5];
  const void* ws_b   = d_in[6];
  const void* wv     = d_in[7];
  const void* edge_index = d_in[8];

  char* ws = (char*)d_ws;
  int*   hist  = (int*)(ws + HIST_OFF);
  int*   fill  = (int*)(ws + FILL_OFF);
  int*   rowptr= (int*)(ws + ROWPTR_OFF);
  int*   perm  = (int*)(ws + PERM_OFF);
  int*   psrc  = (int*)(ws + PSRC_OFF);
  short* PQ    = (short*)(ws + PQ_OFF);
  short* QV    = (short*)(ws + QV_OFF);
  float* whv4  = (float*)(ws + WHV4_OFF);
  short* Wbig  = (short*)(ws + WBIG_OFF);
  short* ns_bf = (short*)(ws + NSBF_OFF);
  short* ANSb  = (short*)(ws + ANSB_OFF);
  short* EAb   = (short*)(ws + EAB_OFF);
  float* AP    = (float*)(ws + AP_OFF);
  float* AEV   = (float*)(ws + AEV_OFF);
  float* NodeS = (float*)(ws + NODES_OFF);
  int*   flags = (int*)(ws + FLAGS_OFF);

  hipMemsetAsync(d_ws, 0, ZERO_BYTES, stream);
  detect_kernel<<<1, 256, 0, stream>>>((const unsigned short*)node_s,
                                       (const int*)edge_index, flags);
  hist_kernel<<<1250, 256, 0, stream>>>(edge_index, flags, hist);
  scan_kernel<<<1, 256, 0, stream>>>(hist, rowptr);
  permute_kernel<<<1250, 256, 0, stream>>>(edge_index, flags, rowptr, fill,
                                           perm, psrc);
  prep_kernel<<<673, 256, 0, stream>>>(ws_w, wh, wv, flags, Wbig, whv4);
  node_pre<<<2500, 256, 0, stream>>>(node_v, wh, wv, node_s, flags,
                                     PQ, QV, ns_bf);
  edge_block<<<10000, 256, 0, stream>>>(edge_v, edge_s, wh, flags, rowptr,
                                        perm, psrc, PQ, ns_bf,
                                        ANSb, EAb, AP, AEV);
  node_gemm<<<157, 256, 0, stream>>>(ANSb, EAb, ns_bf, Wbig, NodeS);
  final_fuse<<<2500, 256, 0, stream>>>(NodeS, AP, AEV, wv, whv4, rowptr,
                                       QV, ws_b, flags, d_out);
}

// Round 7
// 446.627 us; speedup vs baseline: 1.1348x; 1.0438x over previous
//
#include <hip/hip_runtime.h>
#include <hip/hip_bf16.h>

#define N_NODES 10000
#define E_TOT   320000

typedef __attribute__((ext_vector_type(8))) short short8;
typedef __attribute__((ext_vector_type(4))) short s16x4;
typedef __attribute__((ext_vector_type(4))) float f32x4;

// ---- workspace byte offsets (16B-aligned; total ~42.1 MB) ----
#define HIST_OFF    0u            // N int (zeroed)
#define FILL_OFF    40000u        // N int (zeroed)
#define ZERO_BYTES  80000u        // memset [0, here) -- only the sort counters!
#define ROWPTR_OFF  80000u        // (N+1) int (fully written by scan)
#define PERM_OFF    120064u       // E int
#define PSRC_OFF    1400064u      // E int
#define CN_OFF      2680064u      // N*544 shorts: lane-interleaved [ns4|P3|pad]x64, P(h2) tail
#define QARR_OFF    13560064u     // N*208 shorts: Q [d*68+h] + pad4
#define QV_OFF      17720064u     // N*96 bf16
#define WHV4_OFF    19640064u     // 128 f32
#define WBIG_OFF    19640576u     // 256*672 bf16
#define NSBF_OFF    19984640u     // N*256 bf16
#define ANSB_OFF    25104640u     // N*256 bf16  (sum ns[src])/deg
#define EAB_OFF     30224640u     // N*160 bf16  [AES(64)|AVN(68)|pad(28)]/deg
#define AP_OFF      33424640u     // N*204 f32   sum P[src], layout [h*3+d]
#define AEV_OFF     41584640u     // N*12 f32    sum edge_v
#define FLAGS_OFF   42064640u     // 2 ints
// NodeS (N*256 f32 = 10.24MB) aliases [PERM_OFF, ...): perm/psrc/CN are dead
// by the time node_gemm writes it; QARR/QV live above 13.56MB, untouched.
#define NODES_OFF   120064u

union BfS { __hip_bfloat16 h; short s; };
__device__ __forceinline__ short f2bf(float x) { BfS u; u.h = __float2bfloat16(x); return u.s; }
__device__ __forceinline__ float bf(short x) { BfS u; u.s = x; return __bfloat162float(u.h); }
__device__ __forceinline__ float bflo(unsigned u) { return __uint_as_float(u << 16); }
__device__ __forceinline__ float bfhi(unsigned u) { return __uint_as_float(u & 0xffff0000u); }
__device__ __forceinline__ float ldin(const void* p, int f32m, long i) {
  return f32m ? ((const float*)p)[i] : __bfloat162float(((const __hip_bfloat16*)p)[i]);
}
__device__ __forceinline__ int get_ei(const void* p, int i64m, long i) {
  return i64m ? (int)(((const long long*)p)[i]) : ((const int*)p)[i];
}

// ---------------------------------------------------------------------------
__global__ __launch_bounds__(256) void detect_kernel(
    const unsigned short* __restrict__ ns_u16,
    const int* __restrict__ ei_i32, int* __restrict__ flags)
{
  __shared__ int cf, ci;
  if (threadIdx.x == 0) { cf = 0; ci = 0; }
  __syncthreads();
  int c1 = 0;
  for (int i = threadIdx.x; i < 8192; i += 256) {
    unsigned e = (ns_u16[2 * i] >> 7) & 0xFF;
    if (e < 100 || e > 140) c1++;
  }
  int c2 = 0;
  for (int i = threadIdx.x; i < 4096; i += 256)
    if (ei_i32[2 * i + 1] != 0) c2++;
  atomicAdd(&cf, c1); atomicAdd(&ci, c2);
  __syncthreads();
  if (threadIdx.x == 0) {
    flags[0] = (cf > 512) ? 1 : 0;   // 1 => f32 inputs
    flags[1] = (ci < 100) ? 1 : 0;   // 1 => int64 edge_index
  }
}

// ---------------------------------------------------------------------------
__global__ __launch_bounds__(256) void hist_kernel(
    const void* __restrict__ edge_index, const int* __restrict__ flags,
    int* __restrict__ hist)
{
  const int i64m = flags[1];
  int e = blockIdx.x * 256 + threadIdx.x;
  int dst = get_ei(edge_index, i64m, (long)E_TOT + e);
  atomicAdd(&hist[dst], 1);
}

__global__ __launch_bounds__(256) void scan_kernel(
    const int* __restrict__ hist, int* __restrict__ rowptr)
{
  __shared__ int part[256];
  int tid = threadIdx.x;
  int base = tid * 40;
  int s = 0;
  for (int i = 0; i < 40; ++i) { int idx = base + i; if (idx < N_NODES) s += hist[idx]; }
  part[tid] = s;
  __syncthreads();
  for (int off = 1; off < 256; off <<= 1) {
    int v = (tid >= off) ? part[tid - off] : 0;
    __syncthreads();
    part[tid] += v;
    __syncthreads();
  }
  int run = (tid > 0) ? part[tid - 1] : 0;
  for (int i = 0; i < 40; ++i) {
    int idx = base + i;
    if (idx < N_NODES) { rowptr[idx] = run; run += hist[idx]; }
  }
  if (tid == 255) rowptr[N_NODES] = run;
}

__global__ __launch_bounds__(256) void permute_kernel(
    const void* __restrict__ edge_index, const int* __restrict__ flags,
    const int* __restrict__ rowptr, int* __restrict__ fill,
    int* __restrict__ perm, int* __restrict__ psrc)
{
  const int i64m = flags[1];
  int e = blockIdx.x * 256 + threadIdx.x;
  int dst = get_ei(edge_index, i64m, (long)E_TOT + e);
  int src = get_ei(edge_index, i64m, e);
  int pos = rowptr[dst] + atomicAdd(&fill[dst], 1);
  perm[pos] = e; psrc[pos] = src;
}

// ---------------------------------------------------------------------------
// prep: Wbig^T[o][k<672]: k<320 -> ws_w row k; 320..387 -> rows 576..643 (vn);
// 388..415 -> 0; 416..671 -> rows 320..575. Block 672: whv4 = wh[32:36]@wv.
// ---------------------------------------------------------------------------
__global__ __launch_bounds__(256) void prep_kernel(
    const void* __restrict__ ws_w, const void* __restrict__ wh,
    const void* __restrict__ wv, const int* __restrict__ flags,
    short* __restrict__ Wbig, float* __restrict__ whv4)
{
  const int f32m = flags[0];
  int b = blockIdx.x, tid = threadIdx.x;
  if (b < 672) {
    int flat = b * 256 + tid;           // = o*672 + k
    int o = flat / 672, k = flat % 672;
    short v = 0;
    if (k < 320)      v = f2bf(ldin(ws_w, f32m, (long)k * 256 + o));
    else if (k < 388) v = f2bf(ldin(ws_w, f32m, (long)(576 + k - 320) * 256 + o));
    else if (k >= 416) v = f2bf(ldin(ws_w, f32m, (long)(k - 96) * 256 + o));
    Wbig[flat] = v;
  } else if (tid < 128) {
    int q = tid / 32, c = tid % 32;
    float acc = 0.f;
    for (int h = 0; h < 68; ++h)
      acc += ldin(wh, f32m, (32 + q) * 68 + h) * ldin(wv, f32m, h * 32 + c);
    whv4[tid] = acc;
  }
}

// ---------------------------------------------------------------------------
// node_pre: per 4 nodes. Outputs:
//  CN row (544 shorts): k<512: l=k>>3,j=k&7: j<4 -> ns[l*4+j]; j=4..6 ->
//    P(d=j-4,h=l); j=7 -> 0.  k in [512,528): jj=(k-512)>>2,d=k&3: d<3 ->
//    P(d,h=64+jj) else 0.  k>=528 -> 0.
//  QARR row (208 shorts): k<204 -> Q[d*68+h] else 0.
//  nsb row (256 bf16), QV row (96 bf16).
// wh/wv staged in LDS (were per-FMA global loads).
// ---------------------------------------------------------------------------
__global__ __launch_bounds__(256) void node_pre(
    const void* __restrict__ node_v, const void* __restrict__ wh,
    const void* __restrict__ wv, const void* __restrict__ node_s,
    const int* __restrict__ flags,
    short* __restrict__ CN, short* __restrict__ QARR,
    short* __restrict__ QV, short* __restrict__ ns_bf)
{
  const int f32m = flags[0];
  int n0 = blockIdx.x * 4, tid = threadIdx.x;
  __shared__ float whs[68 * 68];
  __shared__ float wvs[68 * 32];
  __shared__ float nv[4][96];
  __shared__ float pq[4][408];
  for (int i = tid; i < 4624; i += 256) whs[i] = ldin(wh, f32m, i);
  for (int i = tid; i < 2176; i += 256) wvs[i] = ldin(wv, f32m, i);
  for (int i = tid; i < 4 * 96; i += 256) nv[i / 96][i % 96] = ldin(node_v, f32m, (long)n0 * 96 + i);
  for (int i = tid; i < 1024; i += 256)
    ns_bf[(long)n0 * 256 + i] = f2bf(ldin(node_s, f32m, (long)n0 * 256 + i));
  __syncthreads();
  for (int o = tid; o < 4 * 408; o += 256) {
    int i = o / 408, r0 = o % 408;
    int part = r0 / 204, r = r0 % 204, d = r / 68, h = r % 68;
    int cbase = part ? 36 : 0;
    float acc = 0.f;
#pragma unroll
    for (int c = 0; c < 32; ++c)
      acc += nv[i][c * 3 + d] * whs[(cbase + c) * 68 + h];
    pq[i][r0] = acc;
  }
  __syncthreads();
  // CN rows
  for (int o = tid; o < 4 * 544; o += 256) {
    int i = o / 544, k = o % 544;
    short v = 0;
    if (k < 512) {
      int l = k >> 3, j = k & 7;
      if (j < 4)      v = f2bf(ldin(node_s, f32m, (long)(n0 + i) * 256 + l * 4 + j));
      else if (j < 7) v = f2bf(pq[i][(j - 4) * 68 + l]);
    } else if (k < 528) {
      int idx = k - 512, jj = idx >> 2, d = idx & 3;
      if (d < 3) v = f2bf(pq[i][d * 68 + 64 + jj]);
    }
    CN[(long)(n0 + i) * 544 + k] = v;
  }
  // QARR rows
  for (int o = tid; o < 4 * 208; o += 256) {
    int i = o / 208, k = o % 208;
    QARR[(long)(n0 + i) * 208 + k] = (k < 204) ? f2bf(pq[i][204 + k]) : (short)0;
  }
  // QV
  for (int o = tid; o < 4 * 96; o += 256) {
    int i = o / 96, r = o % 96, d = r / 32, c = r % 32;
    float acc = 0.f;
    for (int h = 0; h < 68; ++h)
      acc += pq[i][204 + d * 68 + h] * wvs[h * 32 + c];
    QV[(long)(n0 + i) * 96 + r] = f2bf(acc);
  }
}

// ---------------------------------------------------------------------------
// edge_block v3: ONE BLOCK (4 waves) PER DST NODE, stride-4 edge split.
// Per edge: readfirstlane(src,eid) -> SGPR bases; ONE 16B combined-row load
// per lane (ns4 + P3); wave-uniform edge_v via scalar loads (SALU converts).
// Single shared LDS block (passed by pointer -> no template duplication).
// ---------------------------------------------------------------------------
struct EdgeLds {
  float ansL[4][256];
  float apL[4][204];
  float avnL[4][132];
  float aesL[4][64];
  float aevL[4][12];
};

template <int F32M>
__device__ __forceinline__ void edge_body(
    const void* __restrict__ edge_v, const void* __restrict__ edge_s,
    const void* __restrict__ wh,
    const int* __restrict__ rowptr, const int* __restrict__ perm,
    const int* __restrict__ psrc, const short* __restrict__ CN,
    const short* __restrict__ QARR,
    short* __restrict__ ANSb, short* __restrict__ EAb,
    float* __restrict__ AP, float* __restrict__ AEV, EdgeLds* lds)
{
  const int tid = threadIdx.x;
  const int lane = tid & 63, w = tid >> 6;
  const int n = blockIdx.x;
  const int beg = rowptr[n], deg = rowptr[n + 1] - beg;
  const bool has2 = (lane < 4);
  const int h2 = 64 + lane;
  // per-h weight columns wh[32+c][h]
  const float w4a0 = ldin(wh, F32M, 32 * 68 + lane);
  const float w4a1 = ldin(wh, F32M, 33 * 68 + lane);
  const float w4a2 = ldin(wh, F32M, 34 * 68 + lane);
  const float w4a3 = ldin(wh, F32M, 35 * 68 + lane);
  const float w4b0 = has2 ? ldin(wh, F32M, 32 * 68 + h2) : 0.f;
  const float w4b1 = has2 ? ldin(wh, F32M, 33 * 68 + h2) : 0.f;
  const float w4b2 = has2 ? ldin(wh, F32M, 34 * 68 + h2) : 0.f;
  const float w4b3 = has2 ? ldin(wh, F32M, 35 * 68 + h2) : 0.f;
  // Q[dst] channels for this lane's h
  const short* qp = QARR + (long)n * 208;
  const float qa0 = bf(qp[0 * 68 + lane]);
  const float qa1 = bf(qp[1 * 68 + lane]);
  const float qa2 = bf(qp[2 * 68 + lane]);
  const float qb0 = has2 ? bf(qp[0 * 68 + h2]) : 0.f;
  const float qb1 = has2 ? bf(qp[1 * 68 + h2]) : 0.f;
  const float qb2 = has2 ? bf(qp[2 * 68 + h2]) : 0.f;
  float an0 = 0.f, an1 = 0.f, an2 = 0.f, an3 = 0.f;
  float ap0 = 0.f, ap1 = 0.f, ap2 = 0.f;
  float bq0 = 0.f, bq1 = 0.f, bq2 = 0.f;
  float avna = 0.f, avnb = 0.f, aes = 0.f, aev = 0.f;
  int e = w;
  int sv = 0, eid = 0;
  if (e < deg) { sv = psrc[beg + e]; eid = perm[beg + e]; }
  while (e < deg) {
    // prefetch next iteration's indices
    int en = e + 4, svn = 0, eidn = 0;
    if (en < deg) { svn = psrc[beg + en]; eidn = perm[beg + en]; }
    const int sv_s  = __builtin_amdgcn_readfirstlane(sv);
    const int eid_s = __builtin_amdgcn_readfirstlane(eid);
    // wave-uniform edge_v (scalar loads; bf16 converts on SALU)
    float ev0, ev1, ev2, ev3, ev4, ev5, ev6, ev7, ev8, ev9, evA, evB;
    if (F32M) {
      const float* evp = (const float*)edge_v + (long)eid_s * 12;
      ev0 = evp[0]; ev1 = evp[1]; ev2 = evp[2]; ev3 = evp[3];
      ev4 = evp[4]; ev5 = evp[5]; ev6 = evp[6]; ev7 = evp[7];
      ev8 = evp[8]; ev9 = evp[9]; evA = evp[10]; evB = evp[11];
    } else {
      const unsigned* evp = (const unsigned*)((const short*)edge_v + (long)eid_s * 12);
      unsigned u0 = evp[0], u1 = evp[1], u2 = evp[2];
      unsigned u3 = evp[3], u4 = evp[4], u5 = evp[5];
      ev0 = bflo(u0); ev1 = bfhi(u0); ev2 = bflo(u1); ev3 = bfhi(u1);
      ev4 = bflo(u2); ev5 = bfhi(u2); ev6 = bflo(u3); ev7 = bfhi(u3);
      ev8 = bflo(u4); ev9 = bfhi(u4); evA = bflo(u5); evB = bfhi(u5);
    }
    // combined row: one 16B load/lane = [ns*4 | P(h=lane)*3 | pad]
    const short* cs = CN + (long)sv_s * 544;
    short8 cv = *(const short8*)(cs + lane * 8);
    an0 += bf(cv[0]); an1 += bf(cv[1]); an2 += bf(cv[2]); an3 += bf(cv[3]);
    const float pa0 = bf(cv[4]), pa1 = bf(cv[5]), pa2 = bf(cv[6]);
    aes += ldin(edge_s, F32M, (long)eid_s * 64 + lane);
    if (lane < 12) aev += ldin(edge_v, F32M, (long)eid_s * 12 + lane);
    // vh and norm, lane-local (h = lane)
    float v0 = pa0 + qa0 + ev0 * w4a0 + ev3 * w4a1 + ev6 * w4a2 + ev9 * w4a3;
    float v1 = pa1 + qa1 + ev1 * w4a0 + ev4 * w4a1 + ev7 * w4a2 + evA * w4a3;
    float v2 = pa2 + qa2 + ev2 * w4a0 + ev5 * w4a1 + ev8 * w4a2 + evB * w4a3;
    avna += sqrtf(fmaxf(v0 * v0 + v1 * v1 + v2 * v2, 1e-8f));
    ap0 += pa0; ap1 += pa1; ap2 += pa2;
    if (has2) {  // h = 64..67 on lanes 0..3
      s16x4 p2 = *(const s16x4*)(cs + 512 + lane * 4);
      const float pb0 = bf(p2.x), pb1 = bf(p2.y), pb2 = bf(p2.z);
      float u0 = pb0 + qb0 + ev0 * w4b0 + ev3 * w4b1 + ev6 * w4b2 + ev9 * w4b3;
      float u1 = pb1 + qb1 + ev1 * w4b0 + ev4 * w4b1 + ev7 * w4b2 + evA * w4b3;
      float u2 = pb2 + qb2 + ev2 * w4b0 + ev5 * w4b1 + ev8 * w4b2 + evB * w4b3;
      avnb += sqrtf(fmaxf(u0 * u0 + u1 * u1 + u2 * u2, 1e-8f));
      bq0 += pb0; bq1 += pb1; bq2 += pb2;
    }
    e = en; sv = svn; eid = eidn;
  }
  // ---- cross-wave f32 reduction in LDS (one barrier) ----
  lds->ansL[w][lane * 4 + 0] = an0; lds->ansL[w][lane * 4 + 1] = an1;
  lds->ansL[w][lane * 4 + 2] = an2; lds->ansL[w][lane * 4 + 3] = an3;
  lds->apL[w][lane * 3 + 0] = ap0; lds->apL[w][lane * 3 + 1] = ap1;
  lds->apL[w][lane * 3 + 2] = ap2;
  if (has2) {
    lds->apL[w][192 + lane * 3 + 0] = bq0;
    lds->apL[w][192 + lane * 3 + 1] = bq1;
    lds->apL[w][192 + lane * 3 + 2] = bq2;
  }
  lds->avnL[w][lane] = avna;
  if (has2) lds->avnL[w][64 + lane] = avnb;
  lds->aesL[w][lane] = aes;
  if (lane < 12) lds->aevL[w][lane] = aev;
  __syncthreads();
  const float inv = 1.f / fmaxf((float)deg, 1.f);
  {
    float s = lds->ansL[0][tid] + lds->ansL[1][tid] + lds->ansL[2][tid] + lds->ansL[3][tid];
    ANSb[(long)n * 256 + tid] = f2bf(s * inv);
  }
  if (tid < 204) {
    float s = lds->apL[0][tid] + lds->apL[1][tid] + lds->apL[2][tid] + lds->apL[3][tid];
    AP[(long)n * 204 + tid] = s;
  } else if (tid < 216) {
    int c = tid - 204;
    float s = lds->aevL[0][c] + lds->aevL[1][c] + lds->aevL[2][c] + lds->aevL[3][c];
    AEV[(long)n * 12 + c] = s;
  }
  if (tid < 64) {
    float s = lds->aesL[0][tid] + lds->aesL[1][tid] + lds->aesL[2][tid] + lds->aesL[3][tid];
    EAb[(long)n * 160 + tid] = f2bf(s * inv);
  } else if (tid < 132) {
    int c = tid - 64;  // AVN channel 0..67
    float s = lds->avnL[0][c] + lds->avnL[1][c] + lds->avnL[2][c] + lds->avnL[3][c];
    EAb[(long)n * 160 + 64 + c] = f2bf(s * inv);
  } else if (tid < 160) {
    EAb[(long)n * 160 + tid] = 0;  // pad channels 132..159
  }
}

__global__ __launch_bounds__(256) void edge_block(
    const void* __restrict__ edge_v, const void* __restrict__ edge_s,
    const void* __restrict__ wh, const int* __restrict__ flags,
    const int* __restrict__ rowptr, const int* __restrict__ perm,
    const int* __restrict__ psrc, const short* __restrict__ CN,
    const short* __restrict__ QARR,
    short* __restrict__ ANSb, short* __restrict__ EAb,
    float* __restrict__ AP, float* __restrict__ AEV)
{
  __shared__ EdgeLds lds;   // single allocation shared by both template paths
  if (flags[0])
    edge_body<1>(edge_v, edge_s, wh, rowptr, perm, psrc, CN, QARR,
                 ANSb, EAb, AP, AEV, &lds);
  else
    edge_body<0>(edge_v, edge_s, wh, rowptr, perm, psrc, CN, QARR,
                 ANSb, EAb, AP, AEV, &lds);
}

// ---------------------------------------------------------------------------
// node_gemm: NodeS[n] = [ANS/deg | AES/deg|AVN/deg | ns] @ Wbig
// ---------------------------------------------------------------------------
__global__ __launch_bounds__(256) void node_gemm(
    const short* __restrict__ ANSb, const short* __restrict__ EAb,
    const short* __restrict__ nsb, const short* __restrict__ Wbig,
    float* __restrict__ NodeS)
{
  __shared__ __align__(16) short Xs[64 * 40];
  __shared__ __align__(16) short Ws[256 * 40];
  const int tid = threadIdx.x;
  const int n0 = blockIdx.x * 64;
  const int lane = tid & 63, wave = tid >> 6;
  const int frow = lane & 15, fk = (lane >> 4) * 8, q = lane >> 4;
  f32x4 acc[4][4];
#pragma unroll
  for (int ri = 0; ri < 4; ++ri)
#pragma unroll
    for (int ci = 0; ci < 4; ++ci)
      acc[ri][ci] = (f32x4){0.f, 0.f, 0.f, 0.f};
  const int se = tid >> 2, sq = tid & 3;
  const int rn = min(n0 + se, N_NODES - 1);
  for (int s = 0; s < 21; ++s) {
    short8 xv;
    if (s < 8)       xv = *(const short8*)&ANSb[(long)rn * 256 + s * 32 + sq * 8];
    else if (s < 13) xv = *(const short8*)&EAb[(long)rn * 160 + (s - 8) * 32 + sq * 8];
    else             xv = *(const short8*)&nsb[(long)rn * 256 + (s - 13) * 32 + sq * 8];
    *(short8*)&Xs[se * 40 + sq * 8] = xv;
#pragma unroll
    for (int it = 0; it < 4; ++it) {
      int flat = it * 256 + tid;
      int nn = flat >> 2, qq = flat & 3;
      *(short8*)&Ws[nn * 40 + qq * 8] = *(const short8*)&Wbig[nn * 672 + s * 32 + qq * 8];
    }
    __syncthreads();
    short8 a[4];
#pragma unroll
    for (int ri = 0; ri < 4; ++ri)
      a[ri] = *(const short8*)&Xs[(ri * 16 + frow) * 40 + fk];
#pragma unroll
    for (int ci = 0; ci < 4; ++ci) {
      int nn = wave * 64 + ci * 16 + frow;
      short8 b = *(const short8*)&Ws[nn * 40 + fk];
#pragma unroll
      for (int ri = 0; ri < 4; ++ri)
        acc[ri][ci] = __builtin_amdgcn_mfma_f32_16x16x32_bf16(a[ri], b, acc[ri][ci], 0, 0, 0);
    }
    __syncthreads();
  }
#pragma unroll
  for (int ri = 0; ri < 4; ++ri)
#pragma unroll
    for (int rr = 0; rr < 4; ++rr) {
      int row = n0 + ri * 16 + q * 4 + rr;
      if (row < N_NODES) {
#pragma unroll
        for (int ci = 0; ci < 4; ++ci) {
          int col = wave * 64 + ci * 16 + (lane & 15);
          NodeS[(long)row * 256 + col] = acc[ri][ci][rr];
        }
      }
    }
}

// ---------------------------------------------------------------------------
// final_fuse: per 4 nodes — agg_v = AP@wv + AEV@whv4 in LDS, then write all
// 4*352 outputs.
// ---------------------------------------------------------------------------
__global__ __launch_bounds__(256) void final_fuse(
    const float* __restrict__ NodeS, const float* __restrict__ AP,
    const float* __restrict__ AEV, const void* __restrict__ wv,
    const float* __restrict__ whv4, const int* __restrict__ rowptr,
    const short* __restrict__ QV, const void* __restrict__ ws_b,
    const int* __restrict__ flags, void* __restrict__ out)
{
  const int f32m = flags[0];
  int n0 = blockIdx.x * 4, tid = threadIdx.x;
  __shared__ float wvs[68 * 32];
  __shared__ float wh4s[128];
  __shared__ float APs[4][204];
  __shared__ float AEVs[4][12];
  __shared__ float aggL[4][96];
  for (int i = tid; i < 2176; i += 256) wvs[i] = ldin(wv, f32m, i);
  if (tid < 128) wh4s[tid] = whv4[tid];
  for (int i = tid; i < 816; i += 256) APs[i / 204][i % 204] = AP[(long)n0 * 204 + i];
  if (tid < 48) AEVs[tid / 12][tid % 12] = AEV[(long)n0 * 12 + tid];
  __syncthreads();
  for (int o = tid; o < 384; o += 256) {
    int i = o / 96, r = o % 96, c = r / 3, d = r % 3;
    float acc = AEVs[i][d] * wh4s[c] + AEVs[i][3 + d] * wh4s[32 + c]
              + AEVs[i][6 + d] * wh4s[64 + c] + AEVs[i][9 + d] * wh4s[96 + c];
    for (int h = 0; h < 68; ++h)
      acc += APs[i][h * 3 + d] * wvs[h * 32 + c];
    aggL[i][r] = acc;
  }
  __syncthreads();
  for (int o = tid; o < 1408; o += 256) {
    int i = o / 352, j = o % 352;
    int n = n0 + i;
    int deg = rowptr[n + 1] - rowptr[n];
    float v;
    if (j < 256) {
      v = (deg > 0) ? (NodeS[(long)n * 256 + j] + ldin(ws_b, f32m, j)) : 0.f;
    } else {
      int m = j - 256, ch = m / 3, d = m % 3;
      float inv = 1.f / fmaxf((float)deg, 1.f);
      v = aggL[i][m] * inv;
      if (deg > 0) v += bf(QV[(long)n * 96 + d * 32 + ch]);
    }
    long flat = (long)n * 352 + j;
    if (f32m) ((float*)out)[flat] = v;
    else      ((__hip_bfloat16*)out)[flat] = __float2bfloat16(v);
  }
}

extern "C" void kernel_launch(void* const* d_in, const int* in_sizes, int n_in,
                              void* d_out, int out_size, void* d_ws, size_t ws_size,
                              hipStream_t stream) {
  const void* node_s = d_in[0];
  const void* node_v = d_in[1];
  const void* edge_s = d_in[2];
  const void* edge_v = d_in[3];
  const void* wh     = d_in[4];
  const void* ws_w   = d_in[5];
  const void* ws_b   = d_in[6];
  const void* wv     = d_in[7];
  const void* edge_index = d_in[8];

  char* ws = (char*)d_ws;
  int*   hist  = (int*)(ws + HIST_OFF);
  int*   fill  = (int*)(ws + FILL_OFF);
  int*   rowptr= (int*)(ws + ROWPTR_OFF);
  int*   perm  = (int*)(ws + PERM_OFF);
  int*   psrc  = (int*)(ws + PSRC_OFF);
  short* CN    = (short*)(ws + CN_OFF);
  short* QARR  = (short*)(ws + QARR_OFF);
  short* QV    = (short*)(ws + QV_OFF);
  float* whv4  = (float*)(ws + WHV4_OFF);
  short* Wbig  = (short*)(ws + WBIG_OFF);
  short* ns_bf = (short*)(ws + NSBF_OFF);
  short* ANSb  = (short*)(ws + ANSB_OFF);
  short* EAb   = (short*)(ws + EAB_OFF);
  float* AP    = (float*)(ws + AP_OFF);
  float* AEV   = (float*)(ws + AEV_OFF);
  float* NodeS = (float*)(ws + NODES_OFF);
  int*   flags = (int*)(ws + FLAGS_OFF);

  hipMemsetAsync(d_ws, 0, ZERO_BYTES, stream);
  detect_kernel<<<1, 256, 0, stream>>>((const unsigned short*)node_s,
                                       (const int*)edge_index, flags);
  hist_kernel<<<1250, 256, 0, stream>>>(edge_index, flags, hist);
  scan_kernel<<<1, 256, 0, stream>>>(hist, rowptr);
  permute_kernel<<<1250, 256, 0, stream>>>(edge_index, flags, rowptr, fill,
                                           perm, psrc);
  prep_kernel<<<673, 256, 0, stream>>>(ws_w, wh, wv, flags, Wbig, whv4);
  node_pre<<<2500, 256, 0, stream>>>(node_v, wh, wv, node_s, flags,
                                     CN, QARR, QV, ns_bf);
  edge_block<<<10000, 256, 0, stream>>>(edge_v, edge_s, wh, flags, rowptr,
                                        perm, psrc, CN, QARR,
                                        ANSb, EAb, AP, AEV);
  node_gemm<<<157, 256, 0, stream>>>(ANSb, EAb, ns_bf, Wbig, NodeS);
  final_fuse<<<2500, 256, 0, stream>>>(NodeS, AP, AEV, wv, whv4, rowptr,
                                       QV, ws_b, flags, d_out);
}

// Round 8
// 434.111 us; speedup vs baseline: 1.1675x; 1.0288x over previous
//
#include <hip/hip_runtime.h>
#include <hip/hip_bf16.h>

#define N_NODES 10000
#define E_TOT   320000

typedef __attribute__((ext_vector_type(8))) short short8;
typedef __attribute__((ext_vector_type(4))) short s16x4;
typedef __attribute__((ext_vector_type(4))) float f32x4;

// ---- workspace byte offsets (16B-aligned; total ~42.1 MB) ----
#define HIST_OFF    0u            // N int (zeroed)
#define FILL_OFF    40000u        // N int (zeroed)
#define ZERO_BYTES  80000u        // memset [0, here) -- only the sort counters!
#define ROWPTR_OFF  80000u        // (N+1) int (written by scanperm block 0)
#define PERM_OFF    120064u       // E int
#define PSRC_OFF    1400064u      // E int
#define CN_OFF      2680064u      // N*544 shorts: lane-interleaved [ns4|P3|pad]x64, P(h2) tail
#define QARR_OFF    13560064u     // N*208 shorts: Q [d*68+h] + pad4
#define QV_OFF      17720064u     // N*96 bf16
#define WHV4_OFF    19640064u     // 128 f32
#define WBIG_OFF    19640576u     // 256*672 bf16
#define NSBF_OFF    19984640u     // N*256 bf16
#define ANSB_OFF    25104640u     // N*256 bf16  (sum ns[src])/deg
#define EAB_OFF     30224640u     // N*160 bf16  [AES(64)|AVN(68)|pad(28)]/deg
#define AP_OFF      33424640u     // N*204 f32   sum P[src], layout [h*3+d]
#define AEV_OFF     41584640u     // N*12 f32    sum edge_v
#define FLAGS_OFF   42064640u     // 2 ints
// NodeS (N*256 f32 = 10.24MB) aliases [PERM_OFF, ...): perm/psrc/CN are dead
// by the time node_gemm writes it; QARR/QV live above 13.56MB, untouched.
#define NODES_OFF   120064u

union BfS { __hip_bfloat16 h; short s; };
__device__ __forceinline__ short f2bf(float x) { BfS u; u.h = __float2bfloat16(x); return u.s; }
__device__ __forceinline__ float bf(short x) { BfS u; u.s = x; return __bfloat162float(u.h); }
__device__ __forceinline__ float bflo(unsigned u) { return __uint_as_float(u << 16); }
__device__ __forceinline__ float bfhi(unsigned u) { return __uint_as_float(u & 0xffff0000u); }
__device__ __forceinline__ float ldin(const void* p, int f32m, long i) {
  return f32m ? ((const float*)p)[i] : __bfloat162float(((const __hip_bfloat16*)p)[i]);
}
__device__ __forceinline__ int get_ei(const void* p, int i64m, long i) {
  return i64m ? (int)(((const long long*)p)[i]) : ((const int*)p)[i];
}

// ---------------------------------------------------------------------------
// hist_det: per-block self-detect of i64m (ballot over 256 samples of the
// src-array's odd int32 words), then hist atomic. Block 0 also computes both
// flags (f32 via exponent histogram of node_s low-u16s, plus i64m).
// ---------------------------------------------------------------------------
__global__ __launch_bounds__(256) void hist_det(
    const void* __restrict__ edge_index, const unsigned short* __restrict__ ns_u16,
    int* __restrict__ hist, int* __restrict__ flags)
{
  const int tid = threadIdx.x;
  const int* ei = (const int*)edge_index;
  int nz = (ei[2 * tid + 1] != 0) ? 1 : 0;
  unsigned long long m = __ballot(nz);
  __shared__ int cnt4[4];
  if ((tid & 63) == 0) cnt4[tid >> 6] = __popcll(m);
  __syncthreads();
  const int i64m = (cnt4[0] + cnt4[1] + cnt4[2] + cnt4[3]) < 16 ? 1 : 0;
  int e = blockIdx.x * 256 + tid;
  int dst = get_ei(edge_index, i64m, (long)E_TOT + e);
  atomicAdd(&hist[dst], 1);
  if (blockIdx.x == 0) {
    __shared__ int cf;
    if (tid == 0) cf = 0;
    __syncthreads();
    int c1 = 0;
    for (int i = tid; i < 8192; i += 256) {
      unsigned ex = (ns_u16[2 * i] >> 7) & 0xFF;
      if (ex < 100 || ex > 140) c1++;
    }
    atomicAdd(&cf, c1);
    __syncthreads();
    if (tid == 0) { flags[0] = (cf > 512) ? 1 : 0; flags[1] = i64m; }
  }
}

// ---------------------------------------------------------------------------
// scanperm: every block loads the full hist (10000 ints) into LDS, scans it
// locally (exclusive per-thread 40-element ranges, in-place), block 0 writes
// global rowptr, then each block permutes its own 256 edges via LDS rowptr.
// Replaces the serial 1-block scan + separate permute launch.
// ---------------------------------------------------------------------------
__global__ __launch_bounds__(256) void scanperm(
    const void* __restrict__ edge_index, const int* __restrict__ flags,
    const int* __restrict__ hist, int* __restrict__ rowptr,
    int* __restrict__ fill, int* __restrict__ perm, int* __restrict__ psrc)
{
  __shared__ int rp[N_NODES];
  __shared__ int part[256];
  const int tid = threadIdx.x;
  for (int i = tid; i < N_NODES; i += 256) rp[i] = hist[i];
  __syncthreads();
  const int base = tid * 40;
  int s = 0;
  for (int i = 0; i < 40; ++i) { int idx = base + i; if (idx < N_NODES) s += rp[idx]; }
  part[tid] = s;
  __syncthreads();
  for (int off = 1; off < 256; off <<= 1) {
    int v = (tid >= off) ? part[tid - off] : 0;
    __syncthreads();
    part[tid] += v;
    __syncthreads();
  }
  int run = (tid > 0) ? part[tid - 1] : 0;
  for (int i = 0; i < 40; ++i) {
    int idx = base + i;
    if (idx < N_NODES) { int h = rp[idx]; rp[idx] = run; run += h; }
  }
  __syncthreads();
  if (blockIdx.x == 0) {
    for (int i = tid; i < N_NODES; i += 256) rowptr[i] = rp[i];
    if (tid == 0) rowptr[N_NODES] = part[255];
  }
  const int i64m = flags[1];
  int e = blockIdx.x * 256 + tid;
  int dst = get_ei(edge_index, i64m, (long)E_TOT + e);
  int src = get_ei(edge_index, i64m, e);
  int pos = rp[dst] + atomicAdd(&fill[dst], 1);
  perm[pos] = e; psrc[pos] = src;
}

// ---------------------------------------------------------------------------
// node_pre_prep: b<2500 -> node_pre (CN/QARR/QV/nsb per 4 nodes, weights in
// LDS); b in [2500,3172) -> Wbig prep; b==3172 -> whv4.
// ---------------------------------------------------------------------------
__global__ __launch_bounds__(256) void node_pre_prep(
    const void* __restrict__ node_v, const void* __restrict__ wh,
    const void* __restrict__ wv, const void* __restrict__ node_s,
    const void* __restrict__ ws_w, const int* __restrict__ flags,
    short* __restrict__ CN, short* __restrict__ QARR,
    short* __restrict__ QV, short* __restrict__ ns_bf,
    short* __restrict__ Wbig, float* __restrict__ whv4)
{
  const int f32m = flags[0];
  const int b = blockIdx.x, tid = threadIdx.x;
  __shared__ float whs[68 * 68];
  __shared__ float wvs[68 * 32];
  __shared__ float nv[4][96];
  __shared__ float pq[4][408];
  if (b >= 2500) {
    int pb = b - 2500;
    if (pb < 672) {
      int flat = pb * 256 + tid;           // = o*672 + k
      int o = flat / 672, k = flat % 672;
      short v = 0;
      if (k < 320)      v = f2bf(ldin(ws_w, f32m, (long)k * 256 + o));
      else if (k < 388) v = f2bf(ldin(ws_w, f32m, (long)(576 + k - 320) * 256 + o));
      else if (k >= 416) v = f2bf(ldin(ws_w, f32m, (long)(k - 96) * 256 + o));
      Wbig[flat] = v;
    } else if (tid < 128) {
      int q = tid / 32, c = tid % 32;
      float acc = 0.f;
      for (int h = 0; h < 68; ++h)
        acc += ldin(wh, f32m, (32 + q) * 68 + h) * ldin(wv, f32m, h * 32 + c);
      whv4[tid] = acc;
    }
    return;
  }
  int n0 = b * 4;
  for (int i = tid; i < 4624; i += 256) whs[i] = ldin(wh, f32m, i);
  for (int i = tid; i < 2176; i += 256) wvs[i] = ldin(wv, f32m, i);
  for (int i = tid; i < 4 * 96; i += 256) nv[i / 96][i % 96] = ldin(node_v, f32m, (long)n0 * 96 + i);
  for (int i = tid; i < 1024; i += 256)
    ns_bf[(long)n0 * 256 + i] = f2bf(ldin(node_s, f32m, (long)n0 * 256 + i));
  __syncthreads();
  for (int o = tid; o < 4 * 408; o += 256) {
    int i = o / 408, r0 = o % 408;
    int part = r0 / 204, r = r0 % 204, d = r / 68, h = r % 68;
    int cbase = part ? 36 : 0;
    float acc = 0.f;
#pragma unroll
    for (int c = 0; c < 32; ++c)
      acc += nv[i][c * 3 + d] * whs[(cbase + c) * 68 + h];
    pq[i][r0] = acc;
  }
  __syncthreads();
  // CN rows
  for (int o = tid; o < 4 * 544; o += 256) {
    int i = o / 544, k = o % 544;
    short v = 0;
    if (k < 512) {
      int l = k >> 3, j = k & 7;
      if (j < 4)      v = f2bf(ldin(node_s, f32m, (long)(n0 + i) * 256 + l * 4 + j));
      else if (j < 7) v = f2bf(pq[i][(j - 4) * 68 + l]);
    } else if (k < 528) {
      int idx = k - 512, jj = idx >> 2, d = idx & 3;
      if (d < 3) v = f2bf(pq[i][d * 68 + 64 + jj]);
    }
    CN[(long)(n0 + i) * 544 + k] = v;
  }
  // QARR rows
  for (int o = tid; o < 4 * 208; o += 256) {
    int i = o / 208, k = o % 208;
    QARR[(long)(n0 + i) * 208 + k] = (k < 204) ? f2bf(pq[i][204 + k]) : (short)0;
  }
  // QV
  for (int o = tid; o < 4 * 96; o += 256) {
    int i = o / 96, r = o % 96, d = r / 32, c = r % 32;
    float acc = 0.f;
    for (int h = 0; h < 68; ++h)
      acc += pq[i][204 + d * 68 + h] * wvs[h * 32 + c];
    QV[(long)(n0 + i) * 96 + r] = f2bf(acc);
  }
}

// ---------------------------------------------------------------------------
// edge_block v4: ONE BLOCK (4 waves) PER DST NODE, stride-4 split, UNROLL-2:
// both CN/edge loads of a pair (e, e+4) issued before either accumulation
// (safe default index 0 when past deg) -> 2x memory-level parallelism.
// ---------------------------------------------------------------------------
struct EdgeLds {
  float ansL[4][256];
  float apL[4][204];
  float avnL[4][132];
  float aesL[4][64];
  float aevL[4][12];
};

template <int F32M>
__device__ __forceinline__ void edge_body(
    const void* __restrict__ edge_v, const void* __restrict__ edge_s,
    const void* __restrict__ wh,
    const int* __restrict__ rowptr, const int* __restrict__ perm,
    const int* __restrict__ psrc, const short* __restrict__ CN,
    const short* __restrict__ QARR,
    short* __restrict__ ANSb, short* __restrict__ EAb,
    float* __restrict__ AP, float* __restrict__ AEV, EdgeLds* lds)
{
  const int tid = threadIdx.x;
  const int lane = tid & 63, w = tid >> 6;
  const int n = blockIdx.x;
  const int beg = rowptr[n], deg = rowptr[n + 1] - beg;
  const bool has2 = (lane < 4);
  const int h2 = 64 + lane;
  const float w4a0 = ldin(wh, F32M, 32 * 68 + lane);
  const float w4a1 = ldin(wh, F32M, 33 * 68 + lane);
  const float w4a2 = ldin(wh, F32M, 34 * 68 + lane);
  const float w4a3 = ldin(wh, F32M, 35 * 68 + lane);
  const float w4b0 = has2 ? ldin(wh, F32M, 32 * 68 + h2) : 0.f;
  const float w4b1 = has2 ? ldin(wh, F32M, 33 * 68 + h2) : 0.f;
  const float w4b2 = has2 ? ldin(wh, F32M, 34 * 68 + h2) : 0.f;
  const float w4b3 = has2 ? ldin(wh, F32M, 35 * 68 + h2) : 0.f;
  const short* qp = QARR + (long)n * 208;
  const float qa0 = bf(qp[0 * 68 + lane]);
  const float qa1 = bf(qp[1 * 68 + lane]);
  const float qa2 = bf(qp[2 * 68 + lane]);
  const float qb0 = has2 ? bf(qp[0 * 68 + h2]) : 0.f;
  const float qb1 = has2 ? bf(qp[1 * 68 + h2]) : 0.f;
  const float qb2 = has2 ? bf(qp[2 * 68 + h2]) : 0.f;
  float an0 = 0.f, an1 = 0.f, an2 = 0.f, an3 = 0.f;
  float ap0 = 0.f, ap1 = 0.f, ap2 = 0.f;
  float bq0 = 0.f, bq1 = 0.f, bq2 = 0.f;
  float avna = 0.f, avnb = 0.f, aes = 0.f, aev = 0.f;
  int e = w;
  int sv0 = 0, id0 = 0, sv1 = 0, id1 = 0;
  if (e < deg)     { sv0 = psrc[beg + e];     id0 = perm[beg + e]; }
  if (e + 4 < deg) { sv1 = psrc[beg + e + 4]; id1 = perm[beg + e + 4]; }
  while (e < deg) {
    const bool p1 = (e + 4 < deg);
    const int en = e + 8;
    int nsv0 = 0, nid0 = 0, nsv1 = 0, nid1 = 0;
    if (en < deg)     { nsv0 = psrc[beg + en];     nid0 = perm[beg + en]; }
    if (en + 4 < deg) { nsv1 = psrc[beg + en + 4]; nid1 = perm[beg + en + 4]; }
    const int s0 = __builtin_amdgcn_readfirstlane(sv0);
    const int d0 = __builtin_amdgcn_readfirstlane(id0);
    const int s1 = __builtin_amdgcn_readfirstlane(sv1);
    const int d1 = __builtin_amdgcn_readfirstlane(id1);
    // ---- issue all loads for BOTH edges up front ----
    const short* cs0 = CN + (long)s0 * 544;
    const short* cs1 = CN + (long)s1 * 544;
    short8 cva = *(const short8*)(cs0 + lane * 8);
    short8 cvb = *(const short8*)(cs1 + lane * 8);
    float esa = ldin(edge_s, F32M, (long)d0 * 64 + lane);
    float esb = ldin(edge_s, F32M, (long)d1 * 64 + lane);
    float eva_l = 0.f, evb_l = 0.f;
    if (lane < 12) {
      eva_l = ldin(edge_v, F32M, (long)d0 * 12 + lane);
      evb_l = ldin(edge_v, F32M, (long)d1 * 12 + lane);
    }
    // wave-uniform edge_v (scalar loads)
    float a0, a1, a2, a3, a4, a5, a6, a7, a8, a9, aA, aB;
    float b0, b1, b2, b3, b4, b5, b6, b7, b8, b9, bA, bB;
    if (F32M) {
      const float* evp0 = (const float*)edge_v + (long)d0 * 12;
      const float* evp1 = (const float*)edge_v + (long)d1 * 12;
      a0 = evp0[0]; a1 = evp0[1]; a2 = evp0[2]; a3 = evp0[3];
      a4 = evp0[4]; a5 = evp0[5]; a6 = evp0[6]; a7 = evp0[7];
      a8 = evp0[8]; a9 = evp0[9]; aA = evp0[10]; aB = evp0[11];
      b0 = evp1[0]; b1 = evp1[1]; b2 = evp1[2]; b3 = evp1[3];
      b4 = evp1[4]; b5 = evp1[5]; b6 = evp1[6]; b7 = evp1[7];
      b8 = evp1[8]; b9 = evp1[9]; bA = evp1[10]; bB = evp1[11];
    } else {
      const unsigned* e0p = (const unsigned*)((const short*)edge_v + (long)d0 * 12);
      const unsigned* e1p = (const unsigned*)((const short*)edge_v + (long)d1 * 12);
      unsigned u0 = e0p[0], u1 = e0p[1], u2 = e0p[2], u3 = e0p[3], u4 = e0p[4], u5 = e0p[5];
      unsigned v0 = e1p[0], v1 = e1p[1], v2 = e1p[2], v3 = e1p[3], v4 = e1p[4], v5 = e1p[5];
      a0 = bflo(u0); a1 = bfhi(u0); a2 = bflo(u1); a3 = bfhi(u1);
      a4 = bflo(u2); a5 = bfhi(u2); a6 = bflo(u3); a7 = bfhi(u3);
      a8 = bflo(u4); a9 = bfhi(u4); aA = bflo(u5); aB = bfhi(u5);
      b0 = bflo(v0); b1 = bfhi(v0); b2 = bflo(v1); b3 = bfhi(v1);
      b4 = bflo(v2); b5 = bfhi(v2); b6 = bflo(v3); b7 = bfhi(v3);
      b8 = bflo(v4); b9 = bfhi(v4); bA = bflo(v5); bB = bfhi(v5);
    }
    // ---- edge 0 accumulate ----
    {
      an0 += bf(cva[0]); an1 += bf(cva[1]); an2 += bf(cva[2]); an3 += bf(cva[3]);
      const float pa0 = bf(cva[4]), pa1 = bf(cva[5]), pa2 = bf(cva[6]);
      aes += esa; aev += eva_l;
      float v0 = pa0 + qa0 + a0 * w4a0 + a3 * w4a1 + a6 * w4a2 + a9 * w4a3;
      float v1 = pa1 + qa1 + a1 * w4a0 + a4 * w4a1 + a7 * w4a2 + aA * w4a3;
      float v2 = pa2 + qa2 + a2 * w4a0 + a5 * w4a1 + a8 * w4a2 + aB * w4a3;
      avna += sqrtf(fmaxf(v0 * v0 + v1 * v1 + v2 * v2, 1e-8f));
      ap0 += pa0; ap1 += pa1; ap2 += pa2;
      if (has2) {
        s16x4 p2 = *(const s16x4*)(cs0 + 512 + lane * 4);
        const float pb0 = bf(p2.x), pb1 = bf(p2.y), pb2 = bf(p2.z);
        float u0 = pb0 + qb0 + a0 * w4b0 + a3 * w4b1 + a6 * w4b2 + a9 * w4b3;
        float u1 = pb1 + qb1 + a1 * w4b0 + a4 * w4b1 + a7 * w4b2 + aA * w4b3;
        float u2 = pb2 + qb2 + a2 * w4b0 + a5 * w4b1 + a8 * w4b2 + aB * w4b3;
        avnb += sqrtf(fmaxf(u0 * u0 + u1 * u1 + u2 * u2, 1e-8f));
        bq0 += pb0; bq1 += pb1; bq2 += pb2;
      }
    }
    // ---- edge 1 accumulate (wave-uniform guard) ----
    if (p1) {
      an0 += bf(cvb[0]); an1 += bf(cvb[1]); an2 += bf(cvb[2]); an3 += bf(cvb[3]);
      const float pa0 = bf(cvb[4]), pa1 = bf(cvb[5]), pa2 = bf(cvb[6]);
      aes += esb; aev += evb_l;
      float v0 = pa0 + qa0 + b0 * w4a0 + b3 * w4a1 + b6 * w4a2 + b9 * w4a3;
      float v1 = pa1 + qa1 + b1 * w4a0 + b4 * w4a1 + b7 * w4a2 + bA * w4a3;
      float v2 = pa2 + qa2 + b2 * w4a0 + b5 * w4a1 + b8 * w4a2 + bB * w4a3;
      avna += sqrtf(fmaxf(v0 * v0 + v1 * v1 + v2 * v2, 1e-8f));
      ap0 += pa0; ap1 += pa1; ap2 += pa2;
      if (has2) {
        s16x4 p2 = *(const s16x4*)(cs1 + 512 + lane * 4);
        const float pb0 = bf(p2.x), pb1 = bf(p2.y), pb2 = bf(p2.z);
        float u0 = pb0 + qb0 + b0 * w4b0 + b3 * w4b1 + b6 * w4b2 + b9 * w4b3;
        float u1 = pb1 + qb1 + b1 * w4b0 + b4 * w4b1 + b7 * w4b2 + bA * w4b3;
        float u2 = pb2 + qb2 + b2 * w4b0 + b5 * w4b1 + b8 * w4b2 + bB * w4b3;
        avnb += sqrtf(fmaxf(u0 * u0 + u1 * u1 + u2 * u2, 1e-8f));
        bq0 += pb0; bq1 += pb1; bq2 += pb2;
      }
    }
    e = en; sv0 = nsv0; id0 = nid0; sv1 = nsv1; id1 = nid1;
  }
  // ---- cross-wave f32 reduction in LDS (one barrier) ----
  lds->ansL[w][lane * 4 + 0] = an0; lds->ansL[w][lane * 4 + 1] = an1;
  lds->ansL[w][lane * 4 + 2] = an2; lds->ansL[w][lane * 4 + 3] = an3;
  lds->apL[w][lane * 3 + 0] = ap0; lds->apL[w][lane * 3 + 1] = ap1;
  lds->apL[w][lane * 3 + 2] = ap2;
  if (has2) {
    lds->apL[w][192 + lane * 3 + 0] = bq0;
    lds->apL[w][192 + lane * 3 + 1] = bq1;
    lds->apL[w][192 + lane * 3 + 2] = bq2;
  }
  lds->avnL[w][lane] = avna;
  if (has2) lds->avnL[w][64 + lane] = avnb;
  lds->aesL[w][lane] = aes;
  if (lane < 12) lds->aevL[w][lane] = aev;
  __syncthreads();
  const float inv = 1.f / fmaxf((float)deg, 1.f);
  {
    float s = lds->ansL[0][tid] + lds->ansL[1][tid] + lds->ansL[2][tid] + lds->ansL[3][tid];
    ANSb[(long)n * 256 + tid] = f2bf(s * inv);
  }
  if (tid < 204) {
    float s = lds->apL[0][tid] + lds->apL[1][tid] + lds->apL[2][tid] + lds->apL[3][tid];
    AP[(long)n * 204 + tid] = s;
  } else if (tid < 216) {
    int c = tid - 204;
    float s = lds->aevL[0][c] + lds->aevL[1][c] + lds->aevL[2][c] + lds->aevL[3][c];
    AEV[(long)n * 12 + c] = s;
  }
  if (tid < 64) {
    float s = lds->aesL[0][tid] + lds->aesL[1][tid] + lds->aesL[2][tid] + lds->aesL[3][tid];
    EAb[(long)n * 160 + tid] = f2bf(s * inv);
  } else if (tid < 132) {
    int c = tid - 64;
    float s = lds->avnL[0][c] + lds->avnL[1][c] + lds->avnL[2][c] + lds->avnL[3][c];
    EAb[(long)n * 160 + 64 + c] = f2bf(s * inv);
  } else if (tid < 160) {
    EAb[(long)n * 160 + tid] = 0;
  }
}

__global__ __launch_bounds__(256) void edge_block(
    const void* __restrict__ edge_v, const void* __restrict__ edge_s,
    const void* __restrict__ wh, const int* __restrict__ flags,
    const int* __restrict__ rowptr, const int* __restrict__ perm,
    const int* __restrict__ psrc, const short* __restrict__ CN,
    const short* __restrict__ QARR,
    short* __restrict__ ANSb, short* __restrict__ EAb,
    float* __restrict__ AP, float* __restrict__ AEV)
{
  __shared__ EdgeLds lds;
  if (flags[0])
    edge_body<1>(edge_v, edge_s, wh, rowptr, perm, psrc, CN, QARR,
                 ANSb, EAb, AP, AEV, &lds);
  else
    edge_body<0>(edge_v, edge_s, wh, rowptr, perm, psrc, CN, QARR,
                 ANSb, EAb, AP, AEV, &lds);
}

// ---------------------------------------------------------------------------
// node_gemm: NodeS[n] = [ANS/deg | AES/deg|AVN/deg | ns] @ Wbig
// ---------------------------------------------------------------------------
__global__ __launch_bounds__(256) void node_gemm(
    const short* __restrict__ ANSb, const short* __restrict__ EAb,
    const short* __restrict__ nsb, const short* __restrict__ Wbig,
    float* __restrict__ NodeS)
{
  __shared__ __align__(16) short Xs[64 * 40];
  __shared__ __align__(16) short Ws[256 * 40];
  const int tid = threadIdx.x;
  const int n0 = blockIdx.x * 64;
  const int lane = tid & 63, wave = tid >> 6;
  const int frow = lane & 15, fk = (lane >> 4) * 8, q = lane >> 4;
  f32x4 acc[4][4];
#pragma unroll
  for (int ri = 0; ri < 4; ++ri)
#pragma unroll
    for (int ci = 0; ci < 4; ++ci)
      acc[ri][ci] = (f32x4){0.f, 0.f, 0.f, 0.f};
  const int se = tid >> 2, sq = tid & 3;
  const int rn = min(n0 + se, N_NODES - 1);
  for (int s = 0; s < 21; ++s) {
    short8 xv;
    if (s < 8)       xv = *(const short8*)&ANSb[(long)rn * 256 + s * 32 + sq * 8];
    else if (s < 13) xv = *(const short8*)&EAb[(long)rn * 160 + (s - 8) * 32 + sq * 8];
    else             xv = *(const short8*)&nsb[(long)rn * 256 + (s - 13) * 32 + sq * 8];
    *(short8*)&Xs[se * 40 + sq * 8] = xv;
#pragma unroll
    for (int it = 0; it < 4; ++it) {
      int flat = it * 256 + tid;
      int nn = flat >> 2, qq = flat & 3;
      *(short8*)&Ws[nn * 40 + qq * 8] = *(const short8*)&Wbig[nn * 672 + s * 32 + qq * 8];
    }
    __syncthreads();
    short8 a[4];
#pragma unroll
    for (int ri = 0; ri < 4; ++ri)
      a[ri] = *(const short8*)&Xs[(ri * 16 + frow) * 40 + fk];
#pragma unroll
    for (int ci = 0; ci < 4; ++ci) {
      int nn = wave * 64 + ci * 16 + frow;
      short8 b = *(const short8*)&Ws[nn * 40 + fk];
#pragma unroll
      for (int ri = 0; ri < 4; ++ri)
        acc[ri][ci] = __builtin_amdgcn_mfma_f32_16x16x32_bf16(a[ri], b, acc[ri][ci], 0, 0, 0);
    }
    __syncthreads();
  }
#pragma unroll
  for (int ri = 0; ri < 4; ++ri)
#pragma unroll
    for (int rr = 0; rr < 4; ++rr) {
      int row = n0 + ri * 16 + q * 4 + rr;
      if (row < N_NODES) {
#pragma unroll
        for (int ci = 0; ci < 4; ++ci) {
          int col = wave * 64 + ci * 16 + (lane & 15);
          NodeS[(long)row * 256 + col] = acc[ri][ci][rr];
        }
      }
    }
}

// ---------------------------------------------------------------------------
// final_fuse: per 4 nodes — agg_v = AP@wv + AEV@whv4 in LDS, then write all
// 4*352 outputs.
// ---------------------------------------------------------------------------
__global__ __launch_bounds__(256) void final_fuse(
    const float* __restrict__ NodeS, const float* __restrict__ AP,
    const float* __restrict__ AEV, const void* __restrict__ wv,
    const float* __restrict__ whv4, const int* __restrict__ rowptr,
    const short* __restrict__ QV, const void* __restrict__ ws_b,
    const int* __restrict__ flags, void* __restrict__ out)
{
  const int f32m = flags[0];
  int n0 = blockIdx.x * 4, tid = threadIdx.x;
  __shared__ float wvs[68 * 32];
  __shared__ float wh4s[128];
  __shared__ float APs[4][204];
  __shared__ float AEVs[4][12];
  __shared__ float aggL[4][96];
  for (int i = tid; i < 2176; i += 256) wvs[i] = ldin(wv, f32m, i);
  if (tid < 128) wh4s[tid] = whv4[tid];
  for (int i = tid; i < 816; i += 256) APs[i / 204][i % 204] = AP[(long)n0 * 204 + i];
  if (tid < 48) AEVs[tid / 12][tid % 12] = AEV[(long)n0 * 12 + tid];
  __syncthreads();
  for (int o = tid; o < 384; o += 256) {
    int i = o / 96, r = o % 96, c = r / 3, d = r % 3;
    float acc = AEVs[i][d] * wh4s[c] + AEVs[i][3 + d] * wh4s[32 + c]
              + AEVs[i][6 + d] * wh4s[64 + c] + AEVs[i][9 + d] * wh4s[96 + c];
    for (int h = 0; h < 68; ++h)
      acc += APs[i][h * 3 + d] * wvs[h * 32 + c];
    aggL[i][r] = acc;
  }
  __syncthreads();
  for (int o = tid; o < 1408; o += 256) {
    int i = o / 352, j = o % 352;
    int n = n0 + i;
    int deg = rowptr[n + 1] - rowptr[n];
    float v;
    if (j < 256) {
      v = (deg > 0) ? (NodeS[(long)n * 256 + j] + ldin(ws_b, f32m, j)) : 0.f;
    } else {
      int m = j - 256, ch = m / 3, d = m % 3;
      float inv = 1.f / fmaxf((float)deg, 1.f);
      v = aggL[i][m] * inv;
      if (deg > 0) v += bf(QV[(long)n * 96 + d * 32 + ch]);
    }
    long flat = (long)n * 352 + j;
    if (f32m) ((float*)out)[flat] = v;
    else      ((__hip_bfloat16*)out)[flat] = __float2bfloat16(v);
  }
}

extern "C" void kernel_launch(void* const* d_in, const int* in_sizes, int n_in,
                              void* d_out, int out_size, void* d_ws, size_t ws_size,
                              hipStream_t stream) {
  const void* node_s = d_in[0];
  const void* node_v = d_in[1];
  const void* edge_s = d_in[2];
  const void* edge_v = d_in[3];
  const void* wh     = d_in[4];
  const void* ws_w   = d_in[5];
  const void* ws_b   = d_in[6];
  const void* wv     = d_in[7];
  const void* edge_index = d_in[8];

  char* ws = (char*)d_ws;
  int*   hist  = (int*)(ws + HIST_OFF);
  int*   fill  = (int*)(ws + FILL_OFF);
  int*   rowptr= (int*)(ws + ROWPTR_OFF);
  int*   perm  = (int*)(ws + PERM_OFF);
  int*   psrc  = (int*)(ws + PSRC_OFF);
  short* CN    = (short*)(ws + CN_OFF);
  short* QARR  = (short*)(ws + QARR_OFF);
  short* QV    = (short*)(ws + QV_OFF);
  float* whv4  = (float*)(ws + WHV4_OFF);
  short* Wbig  = (short*)(ws + WBIG_OFF);
  short* ns_bf = (short*)(ws + NSBF_OFF);
  short* ANSb  = (short*)(ws + ANSB_OFF);
  short* EAb   = (short*)(ws + EAB_OFF);
  float* AP    = (float*)(ws + AP_OFF);
  float* AEV   = (float*)(ws + AEV_OFF);
  float* NodeS = (float*)(ws + NODES_OFF);
  int*   flags = (int*)(ws + FLAGS_OFF);

  hipMemsetAsync(d_ws, 0, ZERO_BYTES, stream);
  hist_det<<<1250, 256, 0, stream>>>(edge_index, (const unsigned short*)node_s,
                                     hist, flags);
  scanperm<<<1250, 256, 0, stream>>>(edge_index, flags, hist, rowptr, fill,
                                     perm, psrc);
  node_pre_prep<<<3173, 256, 0, stream>>>(node_v, wh, wv, node_s, ws_w, flags,
                                          CN, QARR, QV, ns_bf, Wbig, whv4);
  edge_block<<<10000, 256, 0, stream>>>(edge_v, edge_s, wh, flags, rowptr,
                                        perm, psrc, CN, QARR,
                                        ANSb, EAb, AP, AEV);
  node_gemm<<<157, 256, 0, stream>>>(ANSb, EAb, ns_bf, Wbig, NodeS);
  final_fuse<<<2500, 256, 0, stream>>>(NodeS, AP, AEV, wv, whv4, rowptr,
                                       QV, ws_b, flags, d_out);
}

// Round 9
// 431.235 us; speedup vs baseline: 1.1753x; 1.0067x over previous
//
#include <hip/hip_runtime.h>
#include <hip/hip_bf16.h>

#define N_NODES 10000
#define E_TOT   320000

typedef __attribute__((ext_vector_type(8))) short short8;
typedef __attribute__((ext_vector_type(4))) short s16x4;
typedef __attribute__((ext_vector_type(4))) float f32x4;

// ---- workspace byte offsets (16B-aligned; total ~42.1 MB) ----
#define HIST_OFF    0u            // N int (zeroed)
#define FILL_OFF    40000u        // N int (zeroed)
#define ZERO_BYTES  80000u        // memset [0, here) -- only the sort counters!
#define ROWPTR_OFF  80000u        // (N+1) int (written by scanperm block 0)
#define PERM_OFF    120064u       // E int
#define PSRC_OFF    1400064u      // E int
#define CN_OFF      2680064u      // N*544 shorts: lane-interleaved [ns4|P3|pad]x64, P(h2) tail
#define QARR_OFF    13560064u     // N*208 shorts: Q [d*68+h] + pad4
#define QV_OFF      17720064u     // N*96 bf16
#define WHV4_OFF    19640064u     // 128 f32
#define WBIG_OFF    19640576u     // 256*672 bf16
#define NSBF_OFF    19984640u     // N*256 bf16
#define ANSB_OFF    25104640u     // N*256 bf16  (sum ns[src])/deg
#define EAB_OFF     30224640u     // N*160 bf16  [AES(64)|AVN(68)|pad(28)]/deg
#define AP_OFF      33424640u     // N*204 f32   sum P[src], layout [h*3+d]
#define AEV_OFF     41584640u     // N*12 f32    sum edge_v
#define FLAGS_OFF   42064640u     // 2 ints
// NodeS (N*256 f32 = 10.24MB) aliases [PERM_OFF, ...): perm/psrc/CN are dead
// by the time node_gemm writes it; QARR/QV live above 13.56MB, untouched.
#define NODES_OFF   120064u

union BfS { __hip_bfloat16 h; short s; };
__device__ __forceinline__ short f2bf(float x) { BfS u; u.h = __float2bfloat16(x); return u.s; }
__device__ __forceinline__ float bf(short x) { BfS u; u.s = x; return __bfloat162float(u.h); }
__device__ __forceinline__ float bflo(unsigned u) { return __uint_as_float(u << 16); }
__device__ __forceinline__ float bfhi(unsigned u) { return __uint_as_float(u & 0xffff0000u); }
__device__ __forceinline__ float ldin(const void* p, int f32m, long i) {
  return f32m ? ((const float*)p)[i] : __bfloat162float(((const __hip_bfloat16*)p)[i]);
}
__device__ __forceinline__ int get_ei(const void* p, int i64m, long i) {
  return i64m ? (int)(((const long long*)p)[i]) : ((const int*)p)[i];
}

// ---------------------------------------------------------------------------
// hist_det: per-block self-detect of i64m (ballot over 256 samples of the
// src-array's odd int32 words), then hist atomic. Block 0 also computes both
// flags (f32 via exponent histogram of node_s low-u16s, plus i64m).
// ---------------------------------------------------------------------------
__global__ __launch_bounds__(256) void hist_det(
    const void* __restrict__ edge_index, const unsigned short* __restrict__ ns_u16,
    int* __restrict__ hist, int* __restrict__ flags)
{
  const int tid = threadIdx.x;
  const int* ei = (const int*)edge_index;
  int nz = (ei[2 * tid + 1] != 0) ? 1 : 0;
  unsigned long long m = __ballot(nz);
  __shared__ int cnt4[4];
  if ((tid & 63) == 0) cnt4[tid >> 6] = __popcll(m);
  __syncthreads();
  const int i64m = (cnt4[0] + cnt4[1] + cnt4[2] + cnt4[3]) < 16 ? 1 : 0;
  int e = blockIdx.x * 256 + tid;
  int dst = get_ei(edge_index, i64m, (long)E_TOT + e);
  atomicAdd(&hist[dst], 1);
  if (blockIdx.x == 0) {
    __shared__ int cf;
    if (tid == 0) cf = 0;
    __syncthreads();
    int c1 = 0;
    for (int i = tid; i < 8192; i += 256) {
      unsigned ex = (ns_u16[2 * i] >> 7) & 0xFF;
      if (ex < 100 || ex > 140) c1++;
    }
    atomicAdd(&cf, c1);
    __syncthreads();
    if (tid == 0) { flags[0] = (cf > 512) ? 1 : 0; flags[1] = i64m; }
  }
}

// ---------------------------------------------------------------------------
// scanperm: every block loads the full hist (10000 ints) into LDS, scans it
// locally, block 0 writes global rowptr, then each block permutes its own
// 256 edges via the LDS rowptr.
// ---------------------------------------------------------------------------
__global__ __launch_bounds__(256) void scanperm(
    const void* __restrict__ edge_index, const int* __restrict__ flags,
    const int* __restrict__ hist, int* __restrict__ rowptr,
    int* __restrict__ fill, int* __restrict__ perm, int* __restrict__ psrc)
{
  __shared__ int rp[N_NODES];
  __shared__ int part[256];
  const int tid = threadIdx.x;
  for (int i = tid; i < N_NODES; i += 256) rp[i] = hist[i];
  __syncthreads();
  const int base = tid * 40;
  int s = 0;
  for (int i = 0; i < 40; ++i) { int idx = base + i; if (idx < N_NODES) s += rp[idx]; }
  part[tid] = s;
  __syncthreads();
  for (int off = 1; off < 256; off <<= 1) {
    int v = (tid >= off) ? part[tid - off] : 0;
    __syncthreads();
    part[tid] += v;
    __syncthreads();
  }
  int run = (tid > 0) ? part[tid - 1] : 0;
  for (int i = 0; i < 40; ++i) {
    int idx = base + i;
    if (idx < N_NODES) { int h = rp[idx]; rp[idx] = run; run += h; }
  }
  __syncthreads();
  if (blockIdx.x == 0) {
    for (int i = tid; i < N_NODES; i += 256) rowptr[i] = rp[i];
    if (tid == 0) rowptr[N_NODES] = part[255];
  }
  const int i64m = flags[1];
  int e = blockIdx.x * 256 + tid;
  int dst = get_ei(edge_index, i64m, (long)E_TOT + e);
  int src = get_ei(edge_index, i64m, e);
  int pos = rp[dst] + atomicAdd(&fill[dst], 1);
  perm[pos] = e; psrc[pos] = src;
}

// ---------------------------------------------------------------------------
// node_pre_prep: b<2500 -> node_pre (CN/QARR/QV/nsb per 4 nodes, weights in
// LDS); b in [2500,3172) -> Wbig prep; b==3172 -> whv4.
// ---------------------------------------------------------------------------
__global__ __launch_bounds__(256) void node_pre_prep(
    const void* __restrict__ node_v, const void* __restrict__ wh,
    const void* __restrict__ wv, const void* __restrict__ node_s,
    const void* __restrict__ ws_w, const int* __restrict__ flags,
    short* __restrict__ CN, short* __restrict__ QARR,
    short* __restrict__ QV, short* __restrict__ ns_bf,
    short* __restrict__ Wbig, float* __restrict__ whv4)
{
  const int f32m = flags[0];
  const int b = blockIdx.x, tid = threadIdx.x;
  __shared__ float whs[68 * 68];
  __shared__ float wvs[68 * 32];
  __shared__ float nv[4][96];
  __shared__ float pq[4][408];
  if (b >= 2500) {
    int pb = b - 2500;
    if (pb < 672) {
      int flat = pb * 256 + tid;           // = o*672 + k
      int o = flat / 672, k = flat % 672;
      short v = 0;
      if (k < 320)      v = f2bf(ldin(ws_w, f32m, (long)k * 256 + o));
      else if (k < 388) v = f2bf(ldin(ws_w, f32m, (long)(576 + k - 320) * 256 + o));
      else if (k >= 416) v = f2bf(ldin(ws_w, f32m, (long)(k - 96) * 256 + o));
      Wbig[flat] = v;
    } else if (tid < 128) {
      int q = tid / 32, c = tid % 32;
      float acc = 0.f;
      for (int h = 0; h < 68; ++h)
        acc += ldin(wh, f32m, (32 + q) * 68 + h) * ldin(wv, f32m, h * 32 + c);
      whv4[tid] = acc;
    }
    return;
  }
  int n0 = b * 4;
  for (int i = tid; i < 4624; i += 256) whs[i] = ldin(wh, f32m, i);
  for (int i = tid; i < 2176; i += 256) wvs[i] = ldin(wv, f32m, i);
  for (int i = tid; i < 4 * 96; i += 256) nv[i / 96][i % 96] = ldin(node_v, f32m, (long)n0 * 96 + i);
  for (int i = tid; i < 1024; i += 256)
    ns_bf[(long)n0 * 256 + i] = f2bf(ldin(node_s, f32m, (long)n0 * 256 + i));
  __syncthreads();
  for (int o = tid; o < 4 * 408; o += 256) {
    int i = o / 408, r0 = o % 408;
    int part = r0 / 204, r = r0 % 204, d = r / 68, h = r % 68;
    int cbase = part ? 36 : 0;
    float acc = 0.f;
#pragma unroll
    for (int c = 0; c < 32; ++c)
      acc += nv[i][c * 3 + d] * whs[(cbase + c) * 68 + h];
    pq[i][r0] = acc;
  }
  __syncthreads();
  // CN rows
  for (int o = tid; o < 4 * 544; o += 256) {
    int i = o / 544, k = o % 544;
    short v = 0;
    if (k < 512) {
      int l = k >> 3, j = k & 7;
      if (j < 4)      v = f2bf(ldin(node_s, f32m, (long)(n0 + i) * 256 + l * 4 + j));
      else if (j < 7) v = f2bf(pq[i][(j - 4) * 68 + l]);
    } else if (k < 528) {
      int idx = k - 512, jj = idx >> 2, d = idx & 3;
      if (d < 3) v = f2bf(pq[i][d * 68 + 64 + jj]);
    }
    CN[(long)(n0 + i) * 544 + k] = v;
  }
  // QARR rows
  for (int o = tid; o < 4 * 208; o += 256) {
    int i = o / 208, k = o % 208;
    QARR[(long)(n0 + i) * 208 + k] = (k < 204) ? f2bf(pq[i][204 + k]) : (short)0;
  }
  // QV
  for (int o = tid; o < 4 * 96; o += 256) {
    int i = o / 96, r = o % 96, d = r / 32, c = r % 32;
    float acc = 0.f;
    for (int h = 0; h < 68; ++h)
      acc += pq[i][204 + d * 68 + h] * wvs[h * 32 + c];
    QV[(long)(n0 + i) * 96 + r] = f2bf(acc);
  }
}

// ---------------------------------------------------------------------------
// edge_block v5: ONE BLOCK (4 waves) PER DST NODE, stride-4 split.
// Depth-2 software pipeline: at iteration i, ALL loads for edge i+1 (CN row,
// tail, edge_s, edge_v scalar words) are issued before the accumulate of
// edge i; indices prefetched two ahead. Single accumulate body (no dummy
// pair-loads -> avoids R8's unroll-2 regression).
// ---------------------------------------------------------------------------
struct EdgeLds {
  float ansL[4][256];
  float apL[4][204];
  float avnL[4][132];
  float aesL[4][64];
  float aevL[4][12];
};

template <int F32M>
__device__ __forceinline__ void edge_body(
    const void* __restrict__ edge_v, const void* __restrict__ edge_s,
    const void* __restrict__ wh,
    const int* __restrict__ rowptr, const int* __restrict__ perm,
    const int* __restrict__ psrc, const short* __restrict__ CN,
    const short* __restrict__ QARR,
    short* __restrict__ ANSb, short* __restrict__ EAb,
    float* __restrict__ AP, float* __restrict__ AEV, EdgeLds* lds)
{
  const int tid = threadIdx.x;
  const int lane = tid & 63, w = tid >> 6;
  const int n = blockIdx.x;
  const int beg = rowptr[n], deg = rowptr[n + 1] - beg;
  const bool has2 = (lane < 4);
  const int h2 = 64 + lane;
  const float w4a0 = ldin(wh, F32M, 32 * 68 + lane);
  const float w4a1 = ldin(wh, F32M, 33 * 68 + lane);
  const float w4a2 = ldin(wh, F32M, 34 * 68 + lane);
  const float w4a3 = ldin(wh, F32M, 35 * 68 + lane);
  const float w4b0 = has2 ? ldin(wh, F32M, 32 * 68 + h2) : 0.f;
  const float w4b1 = has2 ? ldin(wh, F32M, 33 * 68 + h2) : 0.f;
  const float w4b2 = has2 ? ldin(wh, F32M, 34 * 68 + h2) : 0.f;
  const float w4b3 = has2 ? ldin(wh, F32M, 35 * 68 + h2) : 0.f;
  const short* qp = QARR + (long)n * 208;
  const float qa0 = bf(qp[0 * 68 + lane]);
  const float qa1 = bf(qp[1 * 68 + lane]);
  const float qa2 = bf(qp[2 * 68 + lane]);
  const float qb0 = has2 ? bf(qp[0 * 68 + h2]) : 0.f;
  const float qb1 = has2 ? bf(qp[1 * 68 + h2]) : 0.f;
  const float qb2 = has2 ? bf(qp[2 * 68 + h2]) : 0.f;
  float an0 = 0.f, an1 = 0.f, an2 = 0.f, an3 = 0.f;
  float ap0 = 0.f, ap1 = 0.f, ap2 = 0.f;
  float bq0 = 0.f, bq1 = 0.f, bq2 = 0.f;
  float avna = 0.f, avnb = 0.f, aes = 0.f, aev = 0.f;

  int e = w;
  int s_cur = 0, d_cur = 0;
  int sv1 = 0, id1 = 0;                  // indices for e+4
  short8 cv = {};
  s16x4 tl = {};
  float es_c = 0.f, evl_c = 0.f;
  float c0 = 0.f, c1 = 0.f, c2 = 0.f, c3 = 0.f, c4 = 0.f, c5 = 0.f;
  float c6 = 0.f, c7 = 0.f, c8 = 0.f, c9 = 0.f, cA = 0.f, cB = 0.f;
  if (e < deg) {
    int sv0 = psrc[beg + e], id0 = perm[beg + e];
    s_cur = __builtin_amdgcn_readfirstlane(sv0);
    d_cur = __builtin_amdgcn_readfirstlane(id0);
    cv = *(const short8*)(CN + (long)s_cur * 544 + lane * 8);
    if (has2) tl = *(const s16x4*)(CN + (long)s_cur * 544 + 512 + lane * 4);
    es_c = ldin(edge_s, F32M, (long)d_cur * 64 + lane);
    if (lane < 12) evl_c = ldin(edge_v, F32M, (long)d_cur * 12 + lane);
    if (F32M) {
      const float* evp = (const float*)edge_v + (long)d_cur * 12;
      c0 = evp[0]; c1 = evp[1]; c2 = evp[2]; c3 = evp[3];
      c4 = evp[4]; c5 = evp[5]; c6 = evp[6]; c7 = evp[7];
      c8 = evp[8]; c9 = evp[9]; cA = evp[10]; cB = evp[11];
    } else {
      const unsigned* evp = (const unsigned*)((const short*)edge_v + (long)d_cur * 12);
      unsigned u0 = evp[0], u1 = evp[1], u2 = evp[2];
      unsigned u3 = evp[3], u4 = evp[4], u5 = evp[5];
      c0 = bflo(u0); c1 = bfhi(u0); c2 = bflo(u1); c3 = bfhi(u1);
      c4 = bflo(u2); c5 = bfhi(u2); c6 = bflo(u3); c7 = bfhi(u3);
      c8 = bflo(u4); c9 = bfhi(u4); cA = bflo(u5); cB = bfhi(u5);
    }
  }
  if (e + 4 < deg) { sv1 = psrc[beg + e + 4]; id1 = perm[beg + e + 4]; }

  while (e < deg) {
    const bool vnext = (e + 4 < deg);     // wave-uniform
    const int sN = vnext ? __builtin_amdgcn_readfirstlane(sv1) : s_cur;
    const int dN = vnext ? __builtin_amdgcn_readfirstlane(id1) : d_cur;
    // ---- issue ALL loads for the NEXT edge ----
    short8 cvn = *(const short8*)(CN + (long)sN * 544 + lane * 8);
    s16x4 tln = {};
    if (has2) tln = *(const s16x4*)(CN + (long)sN * 544 + 512 + lane * 4);
    float es_n = ldin(edge_s, F32M, (long)dN * 64 + lane);
    float evl_n = 0.f;
    if (lane < 12) evl_n = ldin(edge_v, F32M, (long)dN * 12 + lane);
    float n0, n1, n2, n3, n4, n5, n6, n7, n8, n9, nA, nB;
    if (F32M) {
      const float* evp = (const float*)edge_v + (long)dN * 12;
      n0 = evp[0]; n1 = evp[1]; n2 = evp[2]; n3 = evp[3];
      n4 = evp[4]; n5 = evp[5]; n6 = evp[6]; n7 = evp[7];
      n8 = evp[8]; n9 = evp[9]; nA = evp[10]; nB = evp[11];
    } else {
      const unsigned* evp = (const unsigned*)((const short*)edge_v + (long)dN * 12);
      unsigned u0 = evp[0], u1 = evp[1], u2 = evp[2];
      unsigned u3 = evp[3], u4 = evp[4], u5 = evp[5];
      n0 = bflo(u0); n1 = bfhi(u0); n2 = bflo(u1); n3 = bfhi(u1);
      n4 = bflo(u2); n5 = bfhi(u2); n6 = bflo(u3); n7 = bfhi(u3);
      n8 = bflo(u4); n9 = bfhi(u4); nA = bflo(u5); nB = bfhi(u5);
    }
    // prefetch indices for e+8
    if (e + 8 < deg) { sv1 = psrc[beg + e + 8]; id1 = perm[beg + e + 8]; }
    // ---- accumulate CURRENT edge (all operands resident) ----
    an0 += bf(cv[0]); an1 += bf(cv[1]); an2 += bf(cv[2]); an3 += bf(cv[3]);
    const float pa0 = bf(cv[4]), pa1 = bf(cv[5]), pa2 = bf(cv[6]);
    aes += es_c; aev += evl_c;
    float v0 = pa0 + qa0 + c0 * w4a0 + c3 * w4a1 + c6 * w4a2 + c9 * w4a3;
    float v1 = pa1 + qa1 + c1 * w4a0 + c4 * w4a1 + c7 * w4a2 + cA * w4a3;
    float v2 = pa2 + qa2 + c2 * w4a0 + c5 * w4a1 + c8 * w4a2 + cB * w4a3;
    avna += sqrtf(fmaxf(v0 * v0 + v1 * v1 + v2 * v2, 1e-8f));
    ap0 += pa0; ap1 += pa1; ap2 += pa2;
    if (has2) {
      const float pb0 = bf(tl.x), pb1 = bf(tl.y), pb2 = bf(tl.z);
      float u0 = pb0 + qb0 + c0 * w4b0 + c3 * w4b1 + c6 * w4b2 + c9 * w4b3;
      float u1 = pb1 + qb1 + c1 * w4b0 + c4 * w4b1 + c7 * w4b2 + cA * w4b3;
      float u2 = pb2 + qb2 + c2 * w4b0 + c5 * w4b1 + c8 * w4b2 + cB * w4b3;
      avnb += sqrtf(fmaxf(u0 * u0 + u1 * u1 + u2 * u2, 1e-8f));
      bq0 += pb0; bq1 += pb1; bq2 += pb2;
    }
    // ---- rotate ----
    cv = cvn; tl = tln; es_c = es_n; evl_c = evl_n;
    c0 = n0; c1 = n1; c2 = n2; c3 = n3; c4 = n4; c5 = n5;
    c6 = n6; c7 = n7; c8 = n8; c9 = n9; cA = nA; cB = nB;
    s_cur = sN; d_cur = dN;
    e += 4;
  }
  // ---- cross-wave f32 reduction in LDS (one barrier) ----
  lds->ansL[w][lane * 4 + 0] = an0; lds->ansL[w][lane * 4 + 1] = an1;
  lds->ansL[w][lane * 4 + 2] = an2; lds->ansL[w][lane * 4 + 3] = an3;
  lds->apL[w][lane * 3 + 0] = ap0; lds->apL[w][lane * 3 + 1] = ap1;
  lds->apL[w][lane * 3 + 2] = ap2;
  if (has2) {
    lds->apL[w][192 + lane * 3 + 0] = bq0;
    lds->apL[w][192 + lane * 3 + 1] = bq1;
    lds->apL[w][192 + lane * 3 + 2] = bq2;
  }
  lds->avnL[w][lane] = avna;
  if (has2) lds->avnL[w][64 + lane] = avnb;
  lds->aesL[w][lane] = aes;
  if (lane < 12) lds->aevL[w][lane] = aev;
  __syncthreads();
  const float inv = 1.f / fmaxf((float)deg, 1.f);
  {
    float s = lds->ansL[0][tid] + lds->ansL[1][tid] + lds->ansL[2][tid] + lds->ansL[3][tid];
    ANSb[(long)n * 256 + tid] = f2bf(s * inv);
  }
  if (tid < 204) {
    float s = lds->apL[0][tid] + lds->apL[1][tid] + lds->apL[2][tid] + lds->apL[3][tid];
    AP[(long)n * 204 + tid] = s;
  } else if (tid < 216) {
    int c = tid - 204;
    float s = lds->aevL[0][c] + lds->aevL[1][c] + lds->aevL[2][c] + lds->aevL[3][c];
    AEV[(long)n * 12 + c] = s;
  }
  if (tid < 64) {
    float s = lds->aesL[0][tid] + lds->aesL[1][tid] + lds->aesL[2][tid] + lds->aesL[3][tid];
    EAb[(long)n * 160 + tid] = f2bf(s * inv);
  } else if (tid < 132) {
    int c = tid - 64;
    float s = lds->avnL[0][c] + lds->avnL[1][c] + lds->avnL[2][c] + lds->avnL[3][c];
    EAb[(long)n * 160 + 64 + c] = f2bf(s * inv);
  } else if (tid < 160) {
    EAb[(long)n * 160 + tid] = 0;
  }
}

__global__ __launch_bounds__(256) void edge_block(
    const void* __restrict__ edge_v, const void* __restrict__ edge_s,
    const void* __restrict__ wh, const int* __restrict__ flags,
    const int* __restrict__ rowptr, const int* __restrict__ perm,
    const int* __restrict__ psrc, const short* __restrict__ CN,
    const short* __restrict__ QARR,
    short* __restrict__ ANSb, short* __restrict__ EAb,
    float* __restrict__ AP, float* __restrict__ AEV)
{
  __shared__ EdgeLds lds;
  if (flags[0])
    edge_body<1>(edge_v, edge_s, wh, rowptr, perm, psrc, CN, QARR,
                 ANSb, EAb, AP, AEV, &lds);
  else
    edge_body<0>(edge_v, edge_s, wh, rowptr, perm, psrc, CN, QARR,
                 ANSb, EAb, AP, AEV, &lds);
}

// ---------------------------------------------------------------------------
// node_gemm: NodeS[n] = [ANS/deg | AES/deg|AVN/deg | ns] @ Wbig
// ---------------------------------------------------------------------------
__global__ __launch_bounds__(256) void node_gemm(
    const short* __restrict__ ANSb, const short* __restrict__ EAb,
    const short* __restrict__ nsb, const short* __restrict__ Wbig,
    float* __restrict__ NodeS)
{
  __shared__ __align__(16) short Xs[64 * 40];
  __shared__ __align__(16) short Ws[256 * 40];
  const int tid = threadIdx.x;
  const int n0 = blockIdx.x * 64;
  const int lane = tid & 63, wave = tid >> 6;
  const int frow = lane & 15, fk = (lane >> 4) * 8, q = lane >> 4;
  f32x4 acc[4][4];
#pragma unroll
  for (int ri = 0; ri < 4; ++ri)
#pragma unroll
    for (int ci = 0; ci < 4; ++ci)
      acc[ri][ci] = (f32x4){0.f, 0.f, 0.f, 0.f};
  const int se = tid >> 2, sq = tid & 3;
  const int rn = min(n0 + se, N_NODES - 1);
  for (int s = 0; s < 21; ++s) {
    short8 xv;
    if (s < 8)       xv = *(const short8*)&ANSb[(long)rn * 256 + s * 32 + sq * 8];
    else if (s < 13) xv = *(const short8*)&EAb[(long)rn * 160 + (s - 8) * 32 + sq * 8];
    else             xv = *(const short8*)&nsb[(long)rn * 256 + (s - 13) * 32 + sq * 8];
    *(short8*)&Xs[se * 40 + sq * 8] = xv;
#pragma unroll
    for (int it = 0; it < 4; ++it) {
      int flat = it * 256 + tid;
      int nn = flat >> 2, qq = flat & 3;
      *(short8*)&Ws[nn * 40 + qq * 8] = *(const short8*)&Wbig[nn * 672 + s * 32 + qq * 8];
    }
    __syncthreads();
    short8 a[4];
#pragma unroll
    for (int ri = 0; ri < 4; ++ri)
      a[ri] = *(const short8*)&Xs[(ri * 16 + frow) * 40 + fk];
#pragma unroll
    for (int ci = 0; ci < 4; ++ci) {
      int nn = wave * 64 + ci * 16 + frow;
      short8 b = *(const short8*)&Ws[nn * 40 + fk];
#pragma unroll
      for (int ri = 0; ri < 4; ++ri)
        acc[ri][ci] = __builtin_amdgcn_mfma_f32_16x16x32_bf16(a[ri], b, acc[ri][ci], 0, 0, 0);
    }
    __syncthreads();
  }
#pragma unroll
  for (int ri = 0; ri < 4; ++ri)
#pragma unroll
    for (int rr = 0; rr < 4; ++rr) {
      int row = n0 + ri * 16 + q * 4 + rr;
      if (row < N_NODES) {
#pragma unroll
        for (int ci = 0; ci < 4; ++ci) {
          int col = wave * 64 + ci * 16 + (lane & 15);
          NodeS[(long)row * 256 + col] = acc[ri][ci][rr];
        }
      }
    }
}

// ---------------------------------------------------------------------------
// final_fuse: per 4 nodes — agg_v = AP@wv + AEV@whv4 in LDS, then write all
// 4*352 outputs.
// ---------------------------------------------------------------------------
__global__ __launch_bounds__(256) void final_fuse(
    const float* __restrict__ NodeS, const float* __restrict__ AP,
    const float* __restrict__ AEV, const void* __restrict__ wv,
    const float* __restrict__ whv4, const int* __restrict__ rowptr,
    const short* __restrict__ QV, const void* __restrict__ ws_b,
    const int* __restrict__ flags, void* __restrict__ out)
{
  const int f32m = flags[0];
  int n0 = blockIdx.x * 4, tid = threadIdx.x;
  __shared__ float wvs[68 * 32];
  __shared__ float wh4s[128];
  __shared__ float APs[4][204];
  __shared__ float AEVs[4][12];
  __shared__ float aggL[4][96];
  for (int i = tid; i < 2176; i += 256) wvs[i] = ldin(wv, f32m, i);
  if (tid < 128) wh4s[tid] = whv4[tid];
  for (int i = tid; i < 816; i += 256) APs[i / 204][i % 204] = AP[(long)n0 * 204 + i];
  if (tid < 48) AEVs[tid / 12][tid % 12] = AEV[(long)n0 * 12 + tid];
  __syncthreads();
  for (int o = tid; o < 384; o += 256) {
    int i = o / 96, r = o % 96, c = r / 3, d = r % 3;
    float acc = AEVs[i][d] * wh4s[c] + AEVs[i][3 + d] * wh4s[32 + c]
              + AEVs[i][6 + d] * wh4s[64 + c] + AEVs[i][9 + d] * wh4s[96 + c];
    for (int h = 0; h < 68; ++h)
      acc += APs[i][h * 3 + d] * wvs[h * 32 + c];
    aggL[i][r] = acc;
  }
  __syncthreads();
  for (int o = tid; o < 1408; o += 256) {
    int i = o / 352, j = o % 352;
    int n = n0 + i;
    int deg = rowptr[n + 1] - rowptr[n];
    float v;
    if (j < 256) {
      v = (deg > 0) ? (NodeS[(long)n * 256 + j] + ldin(ws_b, f32m, j)) : 0.f;
    } else {
      int m = j - 256, ch = m / 3, d = m % 3;
      float inv = 1.f / fmaxf((float)deg, 1.f);
      v = aggL[i][m] * inv;
      if (deg > 0) v += bf(QV[(long)n * 96 + d * 32 + ch]);
    }
    long flat = (long)n * 352 + j;
    if (f32m) ((float*)out)[flat] = v;
    else      ((__hip_bfloat16*)out)[flat] = __float2bfloat16(v);
  }
}

extern "C" void kernel_launch(void* const* d_in, const int* in_sizes, int n_in,
                              void* d_out, int out_size, void* d_ws, size_t ws_size,
                              hipStream_t stream) {
  const void* node_s = d_in[0];
  const void* node_v = d_in[1];
  const void* edge_s = d_in[2];
  const void* edge_v = d_in[3];
  const void* wh     = d_in[4];
  const void* ws_w   = d_in[5];
  const void* ws_b   = d_in[6];
  const void* wv     = d_in[7];
  const void* edge_index = d_in[8];

  char* ws = (char*)d_ws;
  int*   hist  = (int*)(ws + HIST_OFF);
  int*   fill  = (int*)(ws + FILL_OFF);
  int*   rowptr= (int*)(ws + ROWPTR_OFF);
  int*   perm  = (int*)(ws + PERM_OFF);
  int*   psrc  = (int*)(ws + PSRC_OFF);
  short* CN    = (short*)(ws + CN_OFF);
  short* QARR  = (short*)(ws + QARR_OFF);
  short* QV    = (short*)(ws + QV_OFF);
  float* whv4  = (float*)(ws + WHV4_OFF);
  short* Wbig  = (short*)(ws + WBIG_OFF);
  short* ns_bf = (short*)(ws + NSBF_OFF);
  short* ANSb  = (short*)(ws + ANSB_OFF);
  short* EAb   = (short*)(ws + EAB_OFF);
  float* AP    = (float*)(ws + AP_OFF);
  float* AEV   = (float*)(ws + AEV_OFF);
  float* NodeS = (float*)(ws + NODES_OFF);
  int*   flags = (int*)(ws + FLAGS_OFF);

  hipMemsetAsync(d_ws, 0, ZERO_BYTES, stream);
  hist_det<<<1250, 256, 0, stream>>>(edge_index, (const unsigned short*)node_s,
                                     hist, flags);
  scanperm<<<1250, 256, 0, stream>>>(edge_index, flags, hist, rowptr, fill,
                                     perm, psrc);
  node_pre_prep<<<3173, 256, 0, stream>>>(node_v, wh, wv, node_s, ws_w, flags,
                                          CN, QARR, QV, ns_bf, Wbig, whv4);
  edge_block<<<10000, 256, 0, stream>>>(edge_v, edge_s, wh, flags, rowptr,
                                        perm, psrc, CN, QARR,
                                        ANSb, EAb, AP, AEV);
  node_gemm<<<157, 256, 0, stream>>>(ANSb, EAb, ns_bf, Wbig, NodeS);
  final_fuse<<<2500, 256, 0, stream>>>(NodeS, AP, AEV, wv, whv4, rowptr,
                                       QV, ws_b, flags, d_out);
}